// Round 2
// baseline (852.975 us; speedup 1.0000x reference)
//
#include <hip/hip_runtime.h>
#include <hip/hip_bf16.h>
#include <math.h>

// Problem constants
#define BATCH 4
#define CIN 64
#define HH 128
#define WW 128
#define HWP (HH*WW)   // 16384

// ws layout (floats):
//  OFF  : [4][B][18][HW]              = 4,718,592
//  CAT  : [B][256][HW]                = 16,777,216
//  DWT  : [4][9][64][64]              = 147,456   (dw transposed: [i][k][c][o])
//  OWT  : [4][64][9][18]              = 41,472    (ow transposed: [j][c][tap][o])
//  G    : [B][256]                    = 1,024
//  SCALE: [B][256]                    = 1,024
#define OFF_OFF   0
#define CAT_OFF   4718592
#define DWT_OFF   (CAT_OFF + 16777216)
#define OWT_OFF   (DWT_OFF + 147456)
#define G_OFF     (OWT_OFF + 41472)
#define SCALE_OFF (G_OFF + 1024)

__device__ __forceinline__ int rate_of(int i) {
    return (i == 0) ? 2 : (i == 1) ? 3 : (i == 2) ? 5 : 9;
}

// ---------------------------------------------------------------------------
// Kernel 1: transpose weights so inner-loop weight reads are contiguous
// wave-uniform (scalar-load friendly).
// DWT[((i*9+k)*64+c)*64+o] = dw[((i*64+o)*64+c)*9+k]
// OWT[((j*64+c)*9+tap)*18+o] = ow[((j*18+o)*64+c)*9+tap]
// ---------------------------------------------------------------------------
__global__ __launch_bounds__(256) void transpose_w_kernel(
    const float* __restrict__ dw, const float* __restrict__ ow,
    float* __restrict__ dwT, float* __restrict__ owT)
{
    int idx = blockIdx.x * 256 + threadIdx.x;
    if (idx < 147456) {
        int o = idx & 63;
        int c = (idx >> 6) & 63;
        int k = (idx >> 12) % 9;
        int i = idx / 36864;
        dwT[idx] = dw[((i * 64 + o) * 64 + c) * 9 + k];
    }
    int idx2 = idx - 147456;
    if (idx2 >= 0 && idx2 < 41472) {
        int o = idx2 % 18;
        int r = idx2 / 18;
        int tap = r % 9; r /= 9;
        int c = r & 63;
        int j = r >> 6;
        owT[idx2] = ow[((j * 18 + o) * 64 + c) * 9 + tap];
    }
}

// ---------------------------------------------------------------------------
// Kernel 2: offset conv.  For branch j: OFF[j][b][o][h][w] =
//   relu( sum_{c,tap} x[b,c,..] * ow[j][o][c][tap] + ob[j][o] )
// 1 pixel/thread, hoisted tap addressing, c-loop software-pipelined.
// grid = (W/64=2, H/4=32, 4*B=16), block 256 = 64(w) x 4(h)
// ---------------------------------------------------------------------------
__global__ __launch_bounds__(256) void offset_conv_kernel(
    const float* __restrict__ x, const float* __restrict__ owT,
    const float* __restrict__ ob, float* __restrict__ off)
{
    const int t  = threadIdx.x;
    const int lx = t & 63, ly = t >> 6;
    const int w0 = blockIdx.x * 64 + lx;
    const int h0 = blockIdx.y * 4 + ly;
    const int z  = blockIdx.z;
    const int j  = z >> 2, b = z & 3;
    const int d  = rate_of(j);

    // hoist tap addressing + validity out of the c-loop
    int addr[9]; float msk[9];
#pragma unroll
    for (int tap = 0; tap < 9; ++tap) {
        const int iy = tap / 3, ix = tap % 3;
        const int xx = w0 + (ix - 1) * d;
        const int yy = h0 + (iy - 1) * d;
        const bool v = ((unsigned)xx < (unsigned)WW) && ((unsigned)yy < (unsigned)HH);
        const int xc = min(max(xx, 0), WW - 1);
        const int yc = min(max(yy, 0), HH - 1);
        addr[tap] = yc * WW + xc;
        msk[tap]  = v ? 1.f : 0.f;
    }

    float acc[18];
#pragma unroll
    for (int o = 0; o < 18; ++o) acc[o] = ob[j * 18 + o];

    const float* xb = x + b * CIN * HWP;
    float p[9];
#pragma unroll
    for (int tap = 0; tap < 9; ++tap) p[tap] = xb[addr[tap]];

    for (int c = 0; c < CIN; ++c) {
        // prefetch next channel's 9 taps (clamped so last iter reloads c=63)
        const float* xn = xb + (c < CIN - 1 ? c + 1 : CIN - 1) * HWP;
        float q[9];
#pragma unroll
        for (int tap = 0; tap < 9; ++tap) q[tap] = xn[addr[tap]];

        const float* wp = owT + ((j * 64 + c) * 9) * 18;
#pragma unroll
        for (int tap = 0; tap < 9; ++tap) {
            const float v = p[tap] * msk[tap];
            const float* wt = wp + tap * 18;
#pragma unroll
            for (int o = 0; o < 18; ++o)
                acc[o] = fmaf(v, wt[o], acc[o]);
        }
#pragma unroll
        for (int tap = 0; tap < 9; ++tap) p[tap] = q[tap];
    }

    float* op = off + (size_t)z * 18 * HWP + h0 * WW + w0;
#pragma unroll
    for (int o = 0; o < 18; ++o) op[o * HWP] = fmaxf(acc[o], 0.f);
}

// ---------------------------------------------------------------------------
// Kernel 3: deformable conv, branch i, o-split in halves of 32.
// CAT[b][i*64+o][h][w] = sum_{k,c} bilin(x[b,c], py,px) * dw[i][o][c][k]
// grid = (2 wtile * 2 ohalf = 4, H/4=32, 4*B=16) z = i*4+b, block 256
// c-loop software-pipelined: prefetch c+1's 4 corners during c's FMAs.
// ---------------------------------------------------------------------------
__global__ __launch_bounds__(256) void deform_kernel(
    const float* __restrict__ x, const float* __restrict__ dwT,
    const float* __restrict__ off, float* __restrict__ cat)
{
    const int t  = threadIdx.x;
    const int lx = t & 63, ly = t >> 6;
    const int w     = (blockIdx.x & 1) * 64 + lx;
    const int obase = (blockIdx.x >> 1) * 32;
    const int h  = blockIdx.y * 4 + ly;
    const int z  = blockIdx.z;
    const int i  = z >> 2, b = z & 3;
    const int d  = rate_of(i);
    const int j  = (i + 3) & 3;

    const int p = h * WW + w;
    const float* offp = off + ((size_t)(j * 4 + b) * 18) * HWP + p;
    const float* xb   = x + b * CIN * HWP;

    float acc[32];
#pragma unroll
    for (int o = 0; o < 32; ++o) acc[o] = 0.f;

#pragma unroll
    for (int k = 0; k < 9; ++k) {
        const int iy = k / 3, ix = k % 3;
        float dy = offp[(2 * k) * HWP];
        float dx = offp[(2 * k + 1) * HWP];
        float py = (float)(h + (iy - 1) * d) + dy;
        float px = (float)(w + (ix - 1) * d) + dx;
        float fy0 = floorf(py), fx0 = floorf(px);
        float wy1 = py - fy0, wx1 = px - fx0;
        float wy0 = 1.f - wy1, wx0 = 1.f - wx1;
        int y0 = (int)fy0, x0 = (int)fx0;
        int y1 = y0 + 1,  x1 = x0 + 1;
        bool vy0 = (unsigned)y0 < (unsigned)HH, vy1 = (unsigned)y1 < (unsigned)HH;
        bool vx0 = (unsigned)x0 < (unsigned)WW, vx1 = (unsigned)x1 < (unsigned)WW;
        int yc0 = min(max(y0, 0), HH - 1), yc1 = min(max(y1, 0), HH - 1);
        int xc0 = min(max(x0, 0), WW - 1), xc1 = min(max(x1, 0), WW - 1);
        // fold validity into the bilinear weights; always load clipped addr
        float w00 = (vy0 && vx0) ? wy0 * wx0 : 0.f;
        float w01 = (vy0 && vx1) ? wy0 * wx1 : 0.f;
        float w10 = (vy1 && vx0) ? wy1 * wx0 : 0.f;
        float w11 = (vy1 && vx1) ? wy1 * wx1 : 0.f;
        int a00 = yc0 * WW + xc0, a01 = yc0 * WW + xc1;
        int a10 = yc1 * WW + xc0, a11 = yc1 * WW + xc1;

        const float* wk = dwT + (size_t)(i * 9 + k) * 64 * 64 + obase;

        float p00 = xb[a00], p01 = xb[a01], p10 = xb[a10], p11 = xb[a11];
        for (int c = 0; c < CIN; ++c) {
            // prefetch next channel's corners (uniform pointer bump)
            const float* xn = xb + (c < CIN - 1 ? c + 1 : CIN - 1) * HWP;
            float q00 = xn[a00], q01 = xn[a01], q10 = xn[a10], q11 = xn[a11];

            float v = p00 * w00 + p01 * w01 + p10 * w10 + p11 * w11;
            const float* wc = wk + c * 64;   // 32 consecutive, wave-uniform
#pragma unroll
            for (int o = 0; o < 32; ++o) acc[o] = fmaf(v, wc[o], acc[o]);

            p00 = q00; p01 = q01; p10 = q10; p11 = q11;
        }
    }
    float* cp = cat + ((size_t)(b * 256 + i * 64 + obase)) * HWP + p;
#pragma unroll
    for (int o = 0; o < 32; ++o) cp[(size_t)o * HWP] = acc[o];
}

// ---------------------------------------------------------------------------
// Kernel 4: per-(b,channel) spatial mean of CAT.  1024 blocks x 256 thr.
// ---------------------------------------------------------------------------
__global__ __launch_bounds__(256) void reduce_kernel(
    const float* __restrict__ cat, float* __restrict__ g)
{
    const int bc = blockIdx.x;                 // b*256 + ch
    const float* p = cat + (size_t)bc * HWP;
    float s = 0.f;
    for (int idx = threadIdx.x; idx < HWP; idx += 256) s += p[idx];
#pragma unroll
    for (int o = 32; o > 0; o >>= 1) s += __shfl_down(s, o, 64);
    __shared__ float ls[4];
    if ((threadIdx.x & 63) == 0) ls[threadIdx.x >> 6] = s;
    __syncthreads();
    if (threadIdx.x == 0) {
        g[bc] = (ls[0] + ls[1] + ls[2] + ls[3]) * (1.f / (float)HWP);
    }
}

// ---------------------------------------------------------------------------
// Kernel 5: SE MLP.  scale[b][ch] = 1 + sigmoid( relu(g@W1^T+b1) @ W2^T + b2 )
// single block, 256 threads.
// ---------------------------------------------------------------------------
__global__ __launch_bounds__(256) void se_kernel(
    const float* __restrict__ g,  const float* __restrict__ w1,
    const float* __restrict__ b1, const float* __restrict__ w2,
    const float* __restrict__ b2, float* __restrict__ scale)
{
    __shared__ float gs[1024];
    __shared__ float h1s[256];
    const int t = threadIdx.x;
#pragma unroll
    for (int q = 0; q < 4; ++q) gs[q * 256 + t] = g[q * 256 + t];
    __syncthreads();
    {
        int b = t >> 6, o = t & 63;
        float a = b1[o];
        for (int c = 0; c < 256; ++c)
            a = fmaf(gs[b * 256 + c], w1[o * 256 + c], a);
        h1s[t] = fmaxf(a, 0.f);
    }
    __syncthreads();
#pragma unroll
    for (int q = 0; q < 4; ++q) {
        int idx = q * 256 + t;
        int b = idx >> 8, cc = idx & 255;
        float a = b2[cc];
#pragma unroll 8
        for (int o = 0; o < 64; ++o)
            a = fmaf(h1s[b * 64 + o], w2[cc * 64 + o], a);
        scale[idx] = 1.f + 1.f / (1.f + expf(-a));
    }
}

// ---------------------------------------------------------------------------
// Kernel 6: gated sum epilogue.
// out[b,c,p] = x[b,c,p] + sum_i scale[b, i*64+c] * CAT[b, i*64+c, p]
// grid = 4*64*64 blocks of 256; block handles fixed (b,c), 256 pixels.
// ---------------------------------------------------------------------------
__global__ __launch_bounds__(256) void final_kernel(
    const float* __restrict__ x, const float* __restrict__ cat,
    const float* __restrict__ scale, float* __restrict__ out)
{
    const int gid = blockIdx.x;
    const int p = (gid & 63) * 256 + threadIdx.x;
    const int c = (gid >> 6) & 63;
    const int b = gid >> 12;
    const float s0 = scale[b * 256 + c];
    const float s1 = scale[b * 256 + 64 + c];
    const float s2 = scale[b * 256 + 128 + c];
    const float s3 = scale[b * 256 + 192 + c];
    const float* cb = cat + ((size_t)(b * 256 + c)) * HWP + p;
    float v = x[(size_t)(b * 64 + c) * HWP + p];
    v = fmaf(s0, cb[0 * 64 * HWP], v);
    v = fmaf(s1, cb[1 * 64 * HWP], v);
    v = fmaf(s2, cb[2 * 64 * HWP], v);
    v = fmaf(s3, cb[3 * 64 * HWP], v);
    out[(size_t)(b * 64 + c) * HWP + p] = v;
}

extern "C" void kernel_launch(void* const* d_in, const int* in_sizes, int n_in,
                              void* d_out, int out_size, void* d_ws, size_t ws_size,
                              hipStream_t stream) {
    const float* x  = (const float*)d_in[0];
    const float* dw = (const float*)d_in[1];
    const float* ow = (const float*)d_in[2];
    const float* ob = (const float*)d_in[3];
    const float* w1 = (const float*)d_in[4];
    const float* b1 = (const float*)d_in[5];
    const float* w2 = (const float*)d_in[6];
    const float* b2 = (const float*)d_in[7];
    float* out = (float*)d_out;
    float* ws  = (float*)d_ws;

    float* OFF   = ws + OFF_OFF;
    float* CAT   = ws + CAT_OFF;
    float* DWT   = ws + DWT_OFF;
    float* OWT   = ws + OWT_OFF;
    float* G     = ws + G_OFF;
    float* SCALE = ws + SCALE_OFF;

    transpose_w_kernel<<<738, 256, 0, stream>>>(dw, ow, DWT, OWT);
    offset_conv_kernel<<<dim3(2, 32, 16), 256, 0, stream>>>(x, OWT, ob, OFF);
    deform_kernel<<<dim3(4, 32, 16), 256, 0, stream>>>(x, DWT, OFF, CAT);
    reduce_kernel<<<1024, 256, 0, stream>>>(CAT, G);
    se_kernel<<<1, 256, 0, stream>>>(G, w1, b1, w2, b2, SCALE);
    final_kernel<<<16384, 256, 0, stream>>>(x, CAT, SCALE, out);
}

// Round 3
// 591.416 us; speedup vs baseline: 1.4423x; 1.4423x over previous
//
#include <hip/hip_runtime.h>
#include <hip/hip_bf16.h>
#include <math.h>

// Problem constants
#define BATCH 4
#define CIN 64
#define HH 128
#define WW 128
#define HWP (HH*WW)   // 16384

// ws layout (floats):
//  OFF  : [4][B][18][HW]              = 4,718,592
//  CAT  : [B][256][HW]                = 16,777,216
//  WTB  : [4][64][9][64] bf16 shorts  = 147,456 shorts (fits in old DWT slot)
//  OWT  : [4][64][9][18]              = 41,472
//  G    : [B][256]                    = 1,024
//  SCALE: [B][256]                    = 1,024
#define OFF_OFF   0
#define CAT_OFF   4718592
#define DWT_OFF   (CAT_OFF + 16777216)
#define OWT_OFF   (DWT_OFF + 147456)
#define G_OFF     (OWT_OFF + 41472)
#define SCALE_OFF (G_OFF + 1024)

typedef __attribute__((ext_vector_type(8))) short short8;
typedef __attribute__((ext_vector_type(4))) float f32x4;

__device__ __forceinline__ int rate_of(int i) {
    return (i == 0) ? 2 : (i == 1) ? 3 : (i == 2) ? 5 : 9;
}

// fp32 -> bf16 with round-to-nearest-even (finite inputs only)
__device__ __forceinline__ short f2bf(float f) {
    union { float f; unsigned u; } v; v.f = f;
    unsigned u = v.u + 0x7FFFu + ((v.u >> 16) & 1u);
    return (short)(u >> 16);
}

// ---------------------------------------------------------------------------
// Kernel 1: weight prep.
//  WTB (bf16): WTB[((i*64+o)*9+k)*64+c] = bf16(dw[((i*64+o)*64+c)*9+k])
//     -> A-operand rows: 64 consecutive c per (i,o,k), 16B-loadable.
//  OWT (fp32): OWT[((j*64+c)*9+tap)*18+o] = ow[((j*18+o)*64+c)*9+tap]
// ---------------------------------------------------------------------------
__global__ __launch_bounds__(256) void transpose_w_kernel(
    const float* __restrict__ dw, const float* __restrict__ ow,
    short* __restrict__ wtb, float* __restrict__ owT)
{
    int idx = blockIdx.x * 256 + threadIdx.x;
    if (idx < 147456) {
        int c = idx & 63;
        int k = (idx >> 6) % 9;
        int r = idx / 576;
        int o = r & 63;
        int i = r >> 6;
        wtb[idx] = f2bf(dw[((i * 64 + o) * 64 + c) * 9 + k]);
    }
    int idx2 = idx - 147456;
    if (idx2 >= 0 && idx2 < 41472) {
        int o = idx2 % 18;
        int r = idx2 / 18;
        int tap = r % 9; r /= 9;
        int c = r & 63;
        int j = r >> 6;
        owT[idx2] = ow[((j * 18 + o) * 64 + c) * 9 + tap];
    }
}

// ---------------------------------------------------------------------------
// Kernel 2: offset conv (round-2 structure: 1 px/thread, hoisted taps,
// software-pipelined c loop).  grid (2, 32, 16) z = j*4+b.
// ---------------------------------------------------------------------------
__global__ __launch_bounds__(256) void offset_conv_kernel(
    const float* __restrict__ x, const float* __restrict__ owT,
    const float* __restrict__ ob, float* __restrict__ off)
{
    const int t  = threadIdx.x;
    const int lx = t & 63, ly = t >> 6;
    const int w0 = blockIdx.x * 64 + lx;
    const int h0 = blockIdx.y * 4 + ly;
    const int z  = blockIdx.z;
    const int j  = z >> 2, b = z & 3;
    const int d  = rate_of(j);

    int addr[9]; float msk[9];
#pragma unroll
    for (int tap = 0; tap < 9; ++tap) {
        const int iy = tap / 3, ix = tap % 3;
        const int xx = w0 + (ix - 1) * d;
        const int yy = h0 + (iy - 1) * d;
        const bool v = ((unsigned)xx < (unsigned)WW) && ((unsigned)yy < (unsigned)HH);
        addr[tap] = min(max(yy, 0), HH - 1) * WW + min(max(xx, 0), WW - 1);
        msk[tap]  = v ? 1.f : 0.f;
    }

    float acc[18];
#pragma unroll
    for (int o = 0; o < 18; ++o) acc[o] = ob[j * 18 + o];

    const float* xb = x + b * CIN * HWP;
    float p[9];
#pragma unroll
    for (int tap = 0; tap < 9; ++tap) p[tap] = xb[addr[tap]];

    for (int c = 0; c < CIN; ++c) {
        const float* xn = xb + (c < CIN - 1 ? c + 1 : CIN - 1) * HWP;
        float q[9];
#pragma unroll
        for (int tap = 0; tap < 9; ++tap) q[tap] = xn[addr[tap]];

        const float* wp = owT + ((j * 64 + c) * 9) * 18;
#pragma unroll
        for (int tap = 0; tap < 9; ++tap) {
            const float v = p[tap] * msk[tap];
            const float* wt = wp + tap * 18;
#pragma unroll
            for (int o = 0; o < 18; ++o)
                acc[o] = fmaf(v, wt[o], acc[o]);
        }
#pragma unroll
        for (int tap = 0; tap < 9; ++tap) p[tap] = q[tap];
    }

    float* op = off + (size_t)z * 18 * HWP + h0 * WW + w0;
#pragma unroll
    for (int o = 0; o < 18; ++o) op[o * HWP] = fmaxf(acc[o], 0.f);
}

// ---------------------------------------------------------------------------
// Kernel 3: deformable conv via im2col-in-LDS + bf16 MFMA.
// Block = 256 thr = 4 waves; handles one (b,i) and a 64-pixel tile.
// Per tap k: sample 64px x 64c bilinear -> LDS S[p][72] bf16 (pad keeps
// ds_read_b128 16B-aligned, ~2-way banks), then each wave does
// 2 kchunks x 4 ntiles mfma_f32_16x16x32_bf16, A = WTB rows (global 16B),
// B = S columns (LDS 16B).  Accumulate over 9 taps in 16 VGPRs/lane.
// grid = (256 ptiles, 16 z) z = i*4+b.
// Layouts (HW-verified): A[m=lane&15][k=quad*8+j], B[k=quad*8+j][n=lane&15],
// D[m=quad*4+r][n=lane&15].
// ---------------------------------------------------------------------------
__global__ __launch_bounds__(256) void deform_mfma_kernel(
    const float* __restrict__ x, const short* __restrict__ wtb,
    const float* __restrict__ off, float* __restrict__ cat)
{
    __shared__ __align__(16) short S[64][72];

    const int t    = threadIdx.x;
    const int z    = blockIdx.y;
    const int i    = z >> 2, b = z & 3;
    const int d    = rate_of(i);
    const int j    = (i + 3) & 3;
    const int p0   = blockIdx.x * 64;

    // sampling role: thread -> pixel p (0..63), oct pair {oct, oct+4}
    const int sp   = t & 63;           // local pixel
    const int oct0 = t >> 6;           // c-octet 0..3 (also does oct0+4)
    const int pg   = p0 + sp;          // global pixel index in [0,16384)
    const int ph   = pg >> 7, pw = pg & 127;

    // mfma role
    const int wv   = t >> 6;           // wave id 0..3 -> o-subtile
    const int lane = t & 63;
    const int nl   = lane & 15;        // n within 16
    const int quad = lane >> 4;

    const float* xb   = x + b * CIN * HWP;
    const float* offp = off + ((size_t)(j * 4 + b) * 18) * HWP + pg;

    f32x4 acc[4];
#pragma unroll
    for (int nt = 0; nt < 4; ++nt) acc[nt] = (f32x4){0.f, 0.f, 0.f, 0.f};

    for (int k = 0; k < 9; ++k) {
        // ---- bilinear geometry for this thread's pixel (shared by 16 c) ----
        const int iy = k / 3, ix = k % 3;
        float dy = offp[(2 * k) * HWP];
        float dx = offp[(2 * k + 1) * HWP];
        float py = (float)(ph + (iy - 1) * d) + dy;
        float px = (float)(pw + (ix - 1) * d) + dx;
        float fy0 = floorf(py), fx0 = floorf(px);
        float wy1 = py - fy0, wx1 = px - fx0;
        float wy0 = 1.f - wy1, wx0 = 1.f - wx1;
        int y0 = (int)fy0, x0 = (int)fx0;
        int y1 = y0 + 1,  x1 = x0 + 1;
        bool vy0 = (unsigned)y0 < (unsigned)HH, vy1 = (unsigned)y1 < (unsigned)HH;
        bool vx0 = (unsigned)x0 < (unsigned)WW, vx1 = (unsigned)x1 < (unsigned)WW;
        int yc0 = min(max(y0, 0), HH - 1), yc1 = min(max(y1, 0), HH - 1);
        int xc0 = min(max(x0, 0), WW - 1), xc1 = min(max(x1, 0), WW - 1);
        float w00 = (vy0 && vx0) ? wy0 * wx0 : 0.f;
        float w01 = (vy0 && vx1) ? wy0 * wx1 : 0.f;
        float w10 = (vy1 && vx0) ? wy1 * wx0 : 0.f;
        float w11 = (vy1 && vx1) ? wy1 * wx1 : 0.f;
        int a00 = yc0 * WW + xc0, a01 = yc0 * WW + xc1;
        int a10 = yc1 * WW + xc0, a11 = yc1 * WW + xc1;

        if (k) __syncthreads();   // S consumed by previous tap's MFMAs

        // ---- sample 16 channels (2 octets of 8), pack, 16B LDS writes ----
#pragma unroll
        for (int g = 0; g < 2; ++g) {
            const int cb = (oct0 + 4 * g) * 8;
            short8 pk;
#pragma unroll
            for (int cj = 0; cj < 8; ++cj) {
                const float* xc = xb + (cb + cj) * HWP;
                float v = xc[a00] * w00 + xc[a01] * w01
                        + xc[a10] * w10 + xc[a11] * w11;
                pk[cj] = f2bf(v);
            }
            *(__shared__ short8*)&S[sp][cb] = pk;
        }
        __syncthreads();

        // ---- MFMA: this wave's 16 o-rows x 64 pixels, K=64 over 2 chunks --
        const short* wrow = wtb + ((size_t)((i * 64 + wv * 16 + nl) * 9 + k)) * 64;
#pragma unroll
        for (int q2 = 0; q2 < 2; ++q2) {
            short8 a = *(const short8*)&wrow[q2 * 32 + quad * 8];
#pragma unroll
            for (int nt = 0; nt < 4; ++nt) {
                short8 bfr = *(const __shared__ short8*)&S[nt * 16 + nl][q2 * 32 + quad * 8];
                acc[nt] = __builtin_amdgcn_mfma_f32_16x16x32_bf16(a, bfr, acc[nt], 0, 0, 0);
            }
        }
    }

    // ---- store: D[m=quad*4+r][n=nl] -> CAT[b][i*64 + wv*16 + m][p0 + nt*16 + nl]
    float* cp = cat + ((size_t)(b * 256 + i * 64 + wv * 16 + quad * 4)) * HWP + p0 + nl;
#pragma unroll
    for (int nt = 0; nt < 4; ++nt)
#pragma unroll
        for (int r = 0; r < 4; ++r)
            cp[(size_t)r * HWP + nt * 16] = acc[nt][r];
}

// ---------------------------------------------------------------------------
// Kernel 4: per-(b,channel) spatial mean of CAT.  1024 blocks x 256 thr.
// ---------------------------------------------------------------------------
__global__ __launch_bounds__(256) void reduce_kernel(
    const float* __restrict__ cat, float* __restrict__ g)
{
    const int bc = blockIdx.x;
    const float* p = cat + (size_t)bc * HWP;
    float s = 0.f;
    for (int idx = threadIdx.x; idx < HWP; idx += 256) s += p[idx];
#pragma unroll
    for (int o = 32; o > 0; o >>= 1) s += __shfl_down(s, o, 64);
    __shared__ float ls[4];
    if ((threadIdx.x & 63) == 0) ls[threadIdx.x >> 6] = s;
    __syncthreads();
    if (threadIdx.x == 0) {
        g[bc] = (ls[0] + ls[1] + ls[2] + ls[3]) * (1.f / (float)HWP);
    }
}

// ---------------------------------------------------------------------------
// Kernel 5: SE MLP.
// ---------------------------------------------------------------------------
__global__ __launch_bounds__(256) void se_kernel(
    const float* __restrict__ g,  const float* __restrict__ w1,
    const float* __restrict__ b1, const float* __restrict__ w2,
    const float* __restrict__ b2, float* __restrict__ scale)
{
    __shared__ float gs[1024];
    __shared__ float h1s[256];
    const int t = threadIdx.x;
#pragma unroll
    for (int q = 0; q < 4; ++q) gs[q * 256 + t] = g[q * 256 + t];
    __syncthreads();
    {
        int b = t >> 6, o = t & 63;
        float a = b1[o];
        for (int c = 0; c < 256; ++c)
            a = fmaf(gs[b * 256 + c], w1[o * 256 + c], a);
        h1s[t] = fmaxf(a, 0.f);
    }
    __syncthreads();
#pragma unroll
    for (int q = 0; q < 4; ++q) {
        int idx = q * 256 + t;
        int b = idx >> 8, cc = idx & 255;
        float a = b2[cc];
#pragma unroll 8
        for (int o = 0; o < 64; ++o)
            a = fmaf(h1s[b * 64 + o], w2[cc * 64 + o], a);
        scale[idx] = 1.f + 1.f / (1.f + expf(-a));
    }
}

// ---------------------------------------------------------------------------
// Kernel 6: gated sum epilogue.
// ---------------------------------------------------------------------------
__global__ __launch_bounds__(256) void final_kernel(
    const float* __restrict__ x, const float* __restrict__ cat,
    const float* __restrict__ scale, float* __restrict__ out)
{
    const int gid = blockIdx.x;
    const int p = (gid & 63) * 256 + threadIdx.x;
    const int c = (gid >> 6) & 63;
    const int b = gid >> 12;
    const float s0 = scale[b * 256 + c];
    const float s1 = scale[b * 256 + 64 + c];
    const float s2 = scale[b * 256 + 128 + c];
    const float s3 = scale[b * 256 + 192 + c];
    const float* cb = cat + ((size_t)(b * 256 + c)) * HWP + p;
    float v = x[(size_t)(b * 64 + c) * HWP + p];
    v = fmaf(s0, cb[0 * 64 * HWP], v);
    v = fmaf(s1, cb[1 * 64 * HWP], v);
    v = fmaf(s2, cb[2 * 64 * HWP], v);
    v = fmaf(s3, cb[3 * 64 * HWP], v);
    out[(size_t)(b * 64 + c) * HWP + p] = v;
}

extern "C" void kernel_launch(void* const* d_in, const int* in_sizes, int n_in,
                              void* d_out, int out_size, void* d_ws, size_t ws_size,
                              hipStream_t stream) {
    const float* x  = (const float*)d_in[0];
    const float* dw = (const float*)d_in[1];
    const float* ow = (const float*)d_in[2];
    const float* ob = (const float*)d_in[3];
    const float* w1 = (const float*)d_in[4];
    const float* b1 = (const float*)d_in[5];
    const float* w2 = (const float*)d_in[6];
    const float* b2 = (const float*)d_in[7];
    float* out = (float*)d_out;
    float* ws  = (float*)d_ws;

    float* OFF   = ws + OFF_OFF;
    float* CAT   = ws + CAT_OFF;
    short* WTB   = (short*)(ws + DWT_OFF);
    float* OWT   = ws + OWT_OFF;
    float* G     = ws + G_OFF;
    float* SCALE = ws + SCALE_OFF;

    transpose_w_kernel<<<738, 256, 0, stream>>>(dw, ow, WTB, OWT);
    offset_conv_kernel<<<dim3(2, 32, 16), 256, 0, stream>>>(x, OWT, ob, OFF);
    deform_mfma_kernel<<<dim3(256, 16), 256, 0, stream>>>(x, WTB, OFF, CAT);
    reduce_kernel<<<1024, 256, 0, stream>>>(CAT, G);
    se_kernel<<<1, 256, 0, stream>>>(G, w1, b1, w2, b2, SCALE);
    final_kernel<<<16384, 256, 0, stream>>>(x, CAT, SCALE, out);
}

// Round 4
// 542.395 us; speedup vs baseline: 1.5726x; 1.0904x over previous
//
#include <hip/hip_runtime.h>
#include <hip/hip_bf16.h>
#include <math.h>

// Problem constants
#define BATCH 4
#define CIN 64
#define HH 128
#define WW 128
#define HWP (HH*WW)   // 16384

// ws layout (float indices):
//  OFF : [4][B][18][HW] fp32      at OFF_OFF   (4,718,592 floats)
//  CAT : [B][256][HW]  bf16       at CAT_OFF   (16,777,216 ushorts = 8,388,608 floats)
//  XBF : [B][64][HW]   bf16       at XBF_OFF   (4,194,304 ushorts = 2,097,152 floats)
//        (CAT+XBF packed into the old fp32-CAT slot: 10.5M < 16.7M floats)
//  WTB : [4][64][9][64] bf16      at WTB_OFF
//  OWT : [4][64][9][18] fp32      at OWT_OFF
//  G, SCALE : [B][256] fp32
#define OFF_OFF   0
#define CAT_OFF   4718592
#define XBF_OFF   (CAT_OFF + 8388608)
#define WTB_OFF   (CAT_OFF + 16777216)
#define OWT_OFF   (WTB_OFF + 147456)
#define G_OFF     (OWT_OFF + 41472)
#define SCALE_OFF (G_OFF + 1024)

typedef __attribute__((ext_vector_type(8))) short short8;
typedef __attribute__((ext_vector_type(4))) float f32x4;

__device__ __forceinline__ int rate_of(int i) {
    return (i == 0) ? 2 : (i == 1) ? 3 : (i == 2) ? 5 : 9;
}

// fp32 -> bf16 (RNE, finite inputs only)
__device__ __forceinline__ short f2bf(float f) {
    union { float f; unsigned u; } v; v.f = f;
    unsigned u = v.u + 0x7FFFu + ((v.u >> 16) & 1u);
    return (short)(u >> 16);
}
__device__ __forceinline__ float bf2f(unsigned short u) {
    union { unsigned u; float f; } v; v.u = ((unsigned)u) << 16;
    return v.f;
}

// ---------------------------------------------------------------------------
// Kernel 1: prep — xbf = bf16(x); WTB = bf16 A-layout dw; OWT = fp32 ow^T.
// grid 17122 x 256 covers 4,194,304 + 147,456 + 41,472 elements.
// ---------------------------------------------------------------------------
__global__ __launch_bounds__(256) void prep_kernel(
    const float* __restrict__ x,  const float* __restrict__ dw,
    const float* __restrict__ ow, unsigned short* __restrict__ xbf,
    short* __restrict__ wtb, float* __restrict__ owT)
{
    int idx = blockIdx.x * 256 + threadIdx.x;
    if (idx < 4194304) {
        xbf[idx] = (unsigned short)f2bf(x[idx]);
        return;
    }
    int idx1 = idx - 4194304;
    if (idx1 < 147456) {
        int c = idx1 & 63;
        int k = (idx1 >> 6) % 9;
        int r = idx1 / 576;
        int o = r & 63;
        int i = r >> 6;
        wtb[idx1] = f2bf(dw[((i * 64 + o) * 64 + c) * 9 + k]);
        return;
    }
    int idx2 = idx1 - 147456;
    if (idx2 < 41472) {
        int o = idx2 % 18;
        int r = idx2 / 18;
        int tap = r % 9; r /= 9;
        int c = r & 63;
        int j = r >> 6;
        owT[idx2] = ow[((j * 18 + o) * 64 + c) * 9 + tap];
    }
}

// ---------------------------------------------------------------------------
// Kernel 2: offset conv (1 px/thread, hoisted taps, pipelined c loop),
// now gathering from bf16 x.  grid (2, 32, 16) z = j*4+b.
// ---------------------------------------------------------------------------
__global__ __launch_bounds__(256) void offset_conv_kernel(
    const unsigned short* __restrict__ xbf, const float* __restrict__ owT,
    const float* __restrict__ ob, float* __restrict__ off)
{
    const int t  = threadIdx.x;
    const int lx = t & 63, ly = t >> 6;
    const int w0 = blockIdx.x * 64 + lx;
    const int h0 = blockIdx.y * 4 + ly;
    const int z  = blockIdx.z;
    const int j  = z >> 2, b = z & 3;
    const int d  = rate_of(j);

    int addr[9]; float msk[9];
#pragma unroll
    for (int tap = 0; tap < 9; ++tap) {
        const int iy = tap / 3, ix = tap % 3;
        const int xx = w0 + (ix - 1) * d;
        const int yy = h0 + (iy - 1) * d;
        const bool v = ((unsigned)xx < (unsigned)WW) && ((unsigned)yy < (unsigned)HH);
        addr[tap] = min(max(yy, 0), HH - 1) * WW + min(max(xx, 0), WW - 1);
        msk[tap]  = v ? 1.f : 0.f;
    }

    float acc[18];
#pragma unroll
    for (int o = 0; o < 18; ++o) acc[o] = ob[j * 18 + o];

    const unsigned short* xb = xbf + (size_t)b * CIN * HWP;
    float p[9];
#pragma unroll
    for (int tap = 0; tap < 9; ++tap) p[tap] = bf2f(xb[addr[tap]]);

    for (int c = 0; c < CIN; ++c) {
        const unsigned short* xn = xb + (c < CIN - 1 ? c + 1 : CIN - 1) * HWP;
        float q[9];
#pragma unroll
        for (int tap = 0; tap < 9; ++tap) q[tap] = bf2f(xn[addr[tap]]);

        const float* wp = owT + ((j * 64 + c) * 9) * 18;
#pragma unroll
        for (int tap = 0; tap < 9; ++tap) {
            const float v = p[tap] * msk[tap];
            const float* wt = wp + tap * 18;
#pragma unroll
            for (int o = 0; o < 18; ++o)
                acc[o] = fmaf(v, wt[o], acc[o]);
        }
#pragma unroll
        for (int tap = 0; tap < 9; ++tap) p[tap] = q[tap];
    }

    float* op = off + (size_t)z * 18 * HWP + h0 * WW + w0;
#pragma unroll
    for (int o = 0; o < 18; ++o) op[o * HWP] = fmaxf(acc[o], 0.f);
}

// ---------------------------------------------------------------------------
// Kernel 3: deformable conv, im2col-in-LDS + bf16 MFMA, 2D tiles.
// Block = 256 thr = 4 waves; one (b,i), pixel tile = 2 rows x 64 cols.
// Sampling: thread -> (pixel spx 0..127, channel-half cg); gathers 32 c
// from bf16 x, packs bf16 into S[row][px][72-pad].
// MFMA: wave wv owns o-subtile [wv*16,+16); 8 n-tiles x 2 k-chunks of
// mfma_f32_16x16x32_bf16 per tap; acc 8 x f32x4 = 32 VGPR.
// grid = (128 tiles, 16 z), z = i*4+b.  LDS 18.4 KB -> ~6 blocks/CU.
// Layouts (HW-verified): A[m=lane&15][k=quad*8+j], B[k=quad*8+j][n=lane&15],
// D[m=quad*4+r][n=lane&15].
// ---------------------------------------------------------------------------
__global__ __launch_bounds__(256) void deform_mfma_kernel(
    const unsigned short* __restrict__ xbf, const short* __restrict__ wtb,
    const float* __restrict__ off, unsigned short* __restrict__ cat)
{
    __shared__ __align__(16) short S[2][64][72];   // 18,432 B

    const int t  = threadIdx.x;
    const int z  = blockIdx.y;
    const int i  = z >> 2, b = z & 3;
    const int d  = rate_of(i);
    const int j  = (i + 3) & 3;
    const int ty = blockIdx.x >> 1;    // row-pair 0..63
    const int tx = blockIdx.x & 1;     // col-half 0..1

    // sampling role
    const int spx = t & 127;           // local pixel 0..127
    const int cg  = t >> 7;            // channel half 0..1
    const int sly = spx >> 6, slx = spx & 63;
    const int ph  = ty * 2 + sly, pw = tx * 64 + slx;
    const int pg  = ph * WW + pw;

    // mfma role
    const int wv = t >> 6, lane = t & 63;
    const int nl = lane & 15, quad = lane >> 4;

    const unsigned short* xbb = xbf + (size_t)b * CIN * HWP;
    const float* offp = off + ((size_t)(j * 4 + b) * 18) * HWP + pg;

    f32x4 acc[8];
#pragma unroll
    for (int nt = 0; nt < 8; ++nt) acc[nt] = (f32x4){0.f, 0.f, 0.f, 0.f};

    for (int k = 0; k < 9; ++k) {
        // ---- bilinear geometry for this thread's pixel ----
        const int iy = k / 3, ix = k % 3;
        float dy = offp[(2 * k) * HWP];
        float dx = offp[(2 * k + 1) * HWP];
        float py = (float)(ph + (iy - 1) * d) + dy;
        float px = (float)(pw + (ix - 1) * d) + dx;
        float fy0 = floorf(py), fx0 = floorf(px);
        float wy1 = py - fy0, wx1 = px - fx0;
        float wy0 = 1.f - wy1, wx0 = 1.f - wx1;
        int y0 = (int)fy0, x0 = (int)fx0;
        int y1 = y0 + 1,  x1 = x0 + 1;
        bool vy0 = (unsigned)y0 < (unsigned)HH, vy1 = (unsigned)y1 < (unsigned)HH;
        bool vx0 = (unsigned)x0 < (unsigned)WW, vx1 = (unsigned)x1 < (unsigned)WW;
        int yc0 = min(max(y0, 0), HH - 1), yc1 = min(max(y1, 0), HH - 1);
        int xc0 = min(max(x0, 0), WW - 1), xc1 = min(max(x1, 0), WW - 1);
        float w00 = (vy0 && vx0) ? wy0 * wx0 : 0.f;
        float w01 = (vy0 && vx1) ? wy0 * wx1 : 0.f;
        float w10 = (vy1 && vx0) ? wy1 * wx0 : 0.f;
        float w11 = (vy1 && vx1) ? wy1 * wx1 : 0.f;
        int a00 = yc0 * WW + xc0, a01 = yc0 * WW + xc1;
        int a10 = yc1 * WW + xc0, a11 = yc1 * WW + xc1;

        if (k) __syncthreads();   // previous tap's MFMAs done with S

        // ---- sample this thread's 32 channels (4 chunks of 8) ----
#pragma unroll
        for (int ch = 0; ch < 4; ++ch) {
            const int cb = cg * 32 + ch * 8;
            short8 pk;
#pragma unroll
            for (int cj = 0; cj < 8; ++cj) {
                const unsigned short* xc = xbb + (size_t)(cb + cj) * HWP;
                float v = bf2f(xc[a00]) * w00 + bf2f(xc[a01]) * w01
                        + bf2f(xc[a10]) * w10 + bf2f(xc[a11]) * w11;
                pk[cj] = f2bf(v);
            }
            *(__shared__ short8*)&S[sly][slx][cb] = pk;
        }
        __syncthreads();

        // ---- MFMA: 16 o-rows x 128 pixels, K=64 in 2 chunks ----
        const short* wrow = wtb + ((size_t)((i * 64 + wv * 16 + nl) * 9 + k)) * 64;
#pragma unroll
        for (int q2 = 0; q2 < 2; ++q2) {
            short8 a = *(const short8*)&wrow[q2 * 32 + quad * 8];
#pragma unroll
            for (int nt = 0; nt < 8; ++nt) {
                // pixel = nt*16+nl: LDS row = nt>>2, col = (nt&3)*16+nl
                short8 bfr = *(const __shared__ short8*)
                    &S[nt >> 2][(nt & 3) * 16 + nl][q2 * 32 + quad * 8];
                acc[nt] = __builtin_amdgcn_mfma_f32_16x16x32_bf16(a, bfr, acc[nt], 0, 0, 0);
            }
        }
    }

    // ---- store D[m=quad*4+r][n=nl] as bf16 CAT ----
#pragma unroll
    for (int nt = 0; nt < 8; ++nt) {
        const int prow = ty * 2 + (nt >> 2);
        const int pcol = tx * 64 + (nt & 3) * 16 + nl;
        unsigned short* cp = cat
            + ((size_t)(b * 256 + i * 64 + wv * 16 + quad * 4)) * HWP
            + prow * WW + pcol;
#pragma unroll
        for (int r = 0; r < 4; ++r)
            cp[(size_t)r * HWP] = (unsigned short)f2bf(acc[nt][r]);
    }
}

// ---------------------------------------------------------------------------
// Kernel 4: per-(b,channel) spatial mean of bf16 CAT.  1024 blocks x 256.
// ---------------------------------------------------------------------------
__global__ __launch_bounds__(256) void reduce_kernel(
    const unsigned short* __restrict__ cat, float* __restrict__ g)
{
    const int bc = blockIdx.x;
    const unsigned short* p = cat + (size_t)bc * HWP;
    float s = 0.f;
#pragma unroll
    for (int q = 0; q < 8; ++q) {
        short8 v8 = *(const short8*)(p + q * 2048 + threadIdx.x * 8);
#pragma unroll
        for (int e = 0; e < 8; ++e) s += bf2f((unsigned short)v8[e]);
    }
#pragma unroll
    for (int o = 32; o > 0; o >>= 1) s += __shfl_down(s, o, 64);
    __shared__ float ls[4];
    if ((threadIdx.x & 63) == 0) ls[threadIdx.x >> 6] = s;
    __syncthreads();
    if (threadIdx.x == 0) {
        g[bc] = (ls[0] + ls[1] + ls[2] + ls[3]) * (1.f / (float)HWP);
    }
}

// ---------------------------------------------------------------------------
// Kernel 5: SE MLP.
// ---------------------------------------------------------------------------
__global__ __launch_bounds__(256) void se_kernel(
    const float* __restrict__ g,  const float* __restrict__ w1,
    const float* __restrict__ b1, const float* __restrict__ w2,
    const float* __restrict__ b2, float* __restrict__ scale)
{
    __shared__ float gs[1024];
    __shared__ float h1s[256];
    const int t = threadIdx.x;
#pragma unroll
    for (int q = 0; q < 4; ++q) gs[q * 256 + t] = g[q * 256 + t];
    __syncthreads();
    {
        int b = t >> 6, o = t & 63;
        float a = b1[o];
        for (int c = 0; c < 256; ++c)
            a = fmaf(gs[b * 256 + c], w1[o * 256 + c], a);
        h1s[t] = fmaxf(a, 0.f);
    }
    __syncthreads();
#pragma unroll
    for (int q = 0; q < 4; ++q) {
        int idx = q * 256 + t;
        int b = idx >> 8, cc = idx & 255;
        float a = b2[cc];
#pragma unroll 8
        for (int o = 0; o < 64; ++o)
            a = fmaf(h1s[b * 64 + o], w2[cc * 64 + o], a);
        scale[idx] = 1.f + 1.f / (1.f + expf(-a));
    }
}

// ---------------------------------------------------------------------------
// Kernel 6: gated sum epilogue (bf16 CAT).
// out[b,c,p] = x[b,c,p] + sum_i scale[b,i*64+c] * CAT[b,i*64+c,p]
// ---------------------------------------------------------------------------
__global__ __launch_bounds__(256) void final_kernel(
    const float* __restrict__ x, const unsigned short* __restrict__ cat,
    const float* __restrict__ scale, float* __restrict__ out)
{
    const int gid = blockIdx.x;
    const int p = (gid & 63) * 256 + threadIdx.x;
    const int c = (gid >> 6) & 63;
    const int b = gid >> 12;
    const float s0 = scale[b * 256 + c];
    const float s1 = scale[b * 256 + 64 + c];
    const float s2 = scale[b * 256 + 128 + c];
    const float s3 = scale[b * 256 + 192 + c];
    const unsigned short* cb = cat + ((size_t)(b * 256 + c)) * HWP + p;
    float v = x[(size_t)(b * 64 + c) * HWP + p];
    v = fmaf(s0, bf2f(cb[0 * 64 * HWP]), v);
    v = fmaf(s1, bf2f(cb[1 * 64 * HWP]), v);
    v = fmaf(s2, bf2f(cb[2 * 64 * HWP]), v);
    v = fmaf(s3, bf2f(cb[3 * 64 * HWP]), v);
    out[(size_t)(b * 64 + c) * HWP + p] = v;
}

extern "C" void kernel_launch(void* const* d_in, const int* in_sizes, int n_in,
                              void* d_out, int out_size, void* d_ws, size_t ws_size,
                              hipStream_t stream) {
    const float* x  = (const float*)d_in[0];
    const float* dw = (const float*)d_in[1];
    const float* ow = (const float*)d_in[2];
    const float* ob = (const float*)d_in[3];
    const float* w1 = (const float*)d_in[4];
    const float* b1 = (const float*)d_in[5];
    const float* w2 = (const float*)d_in[6];
    const float* b2 = (const float*)d_in[7];
    float* out = (float*)d_out;
    float* ws  = (float*)d_ws;

    float* OFF           = ws + OFF_OFF;
    unsigned short* CAT  = (unsigned short*)(ws + CAT_OFF);
    unsigned short* XBF  = (unsigned short*)(ws + XBF_OFF);
    short* WTB           = (short*)(ws + WTB_OFF);
    float* OWT           = ws + OWT_OFF;
    float* G             = ws + G_OFF;
    float* SCALE         = ws + SCALE_OFF;

    prep_kernel<<<17122, 256, 0, stream>>>(x, dw, ow, XBF, WTB, OWT);
    offset_conv_kernel<<<dim3(2, 32, 16), 256, 0, stream>>>(XBF, OWT, ob, OFF);
    deform_mfma_kernel<<<dim3(128, 16), 256, 0, stream>>>(XBF, WTB, OFF, CAT);
    reduce_kernel<<<1024, 256, 0, stream>>>(CAT, G);
    se_kernel<<<1, 256, 0, stream>>>(G, w1, b1, w2, b2, SCALE);
    final_kernel<<<16384, 256, 0, stream>>>(x, CAT, SCALE, out);
}

// Round 5
// 366.080 us; speedup vs baseline: 2.3300x; 1.4816x over previous
//
#include <hip/hip_runtime.h>
#include <hip/hip_bf16.h>
#include <math.h>

// Problem constants
#define BATCH 4
#define CIN 64
#define HH 128
#define WW 128
#define HWP (HH*WW)   // 16384

// ws layout (float indices):
//  OFF  : [4][B][18][HW] fp32     at OFF_OFF   (4,718,592 floats)
//  CAT  : [B][256][HW]  bf16      at CAT_OFF   (16,777,216 ushorts = 8,388,608 floats)
//  XBF  : [B][64][HW]   bf16      at XBF_OFF   (4,194,304 ushorts = 2,097,152 floats)
//  XHWC : [B][HW][64]   bf16      at XHWC_OFF  (4,194,304 ushorts = 2,097,152 floats)
//        (CAT+XBF+XHWC packed into the old fp32-CAT slot: 12.6M < 16.7M floats)
//  WTB  : [4][64][9][64] bf16     at WTB_OFF
//  OWT  : [4][64][9][18] fp32     at OWT_OFF
//  G, SCALE : [B][256] fp32
#define OFF_OFF   0
#define CAT_OFF   4718592
#define XBF_OFF   (CAT_OFF + 8388608)
#define XHWC_OFF  (XBF_OFF + 2097152)
#define WTB_OFF   (CAT_OFF + 16777216)
#define OWT_OFF   (WTB_OFF + 147456)
#define G_OFF     (OWT_OFF + 41472)
#define SCALE_OFF (G_OFF + 1024)

typedef __attribute__((ext_vector_type(8))) short short8;
typedef __attribute__((ext_vector_type(8))) unsigned short ushort8;
typedef __attribute__((ext_vector_type(4))) float f32x4;

__device__ __forceinline__ int rate_of(int i) {
    return (i == 0) ? 2 : (i == 1) ? 3 : (i == 2) ? 5 : 9;
}

// fp32 -> bf16 (RNE, finite inputs only)
__device__ __forceinline__ short f2bf(float f) {
    union { float f; unsigned u; } v; v.f = f;
    unsigned u = v.u + 0x7FFFu + ((v.u >> 16) & 1u);
    return (short)(u >> 16);
}
__device__ __forceinline__ float bf2f(unsigned short u) {
    union { unsigned u; float f; } v; v.u = ((unsigned)u) << 16;
    return v.f;
}

// ---------------------------------------------------------------------------
// Kernel 1: prep — XBF = bf16(x) [NCHW]; WTB = bf16 A-layout dw; OWT fp32.
// ---------------------------------------------------------------------------
__global__ __launch_bounds__(256) void prep_kernel(
    const float* __restrict__ x,  const float* __restrict__ dw,
    const float* __restrict__ ow, unsigned short* __restrict__ xbf,
    short* __restrict__ wtb, float* __restrict__ owT)
{
    int idx = blockIdx.x * 256 + threadIdx.x;
    if (idx < 4194304) {
        xbf[idx] = (unsigned short)f2bf(x[idx]);
        return;
    }
    int idx1 = idx - 4194304;
    if (idx1 < 147456) {
        int c = idx1 & 63;
        int k = (idx1 >> 6) % 9;
        int r = idx1 / 576;
        int o = r & 63;
        int i = r >> 6;
        wtb[idx1] = f2bf(dw[((i * 64 + o) * 64 + c) * 9 + k]);
        return;
    }
    int idx2 = idx1 - 147456;
    if (idx2 < 41472) {
        int o = idx2 % 18;
        int r = idx2 / 18;
        int tap = r % 9; r /= 9;
        int c = r & 63;
        int j = r >> 6;
        owT[idx2] = ow[((j * 18 + o) * 64 + c) * 9 + tap];
    }
}

// ---------------------------------------------------------------------------
// Kernel 1b: XHWC[b][p][c] = bf16(x[b][c][p]) — channel-last copy for the
// deform gathers.  Reads coalesced per wave (lanes = consecutive px, fixed
// c), writes 16B/lane.  grid (256 px-tiles, 4 b), block 256.
// ---------------------------------------------------------------------------
__global__ __launch_bounds__(256) void xhwc_kernel(
    const float* __restrict__ x, unsigned short* __restrict__ xhwc)
{
    const int t  = threadIdx.x;
    const int b  = blockIdx.y;
    const int p0 = blockIdx.x * 64;
    const int px = t & 63;          // lane -> pixel (coalesced reads)
    const int cO = t >> 6;          // wave -> c-octet base

    const float* xb = x + (size_t)b * CIN * HWP + p0 + px;
    unsigned short* xh = xhwc + ((size_t)b * HWP + p0 + px) * 64;

#pragma unroll
    for (int g = 0; g < 2; ++g) {
        const int cb = cO * 8 + g * 32;
        ushort8 v;
#pragma unroll
        for (int cj = 0; cj < 8; ++cj)
            v[cj] = (unsigned short)f2bf(xb[(size_t)(cb + cj) * HWP]);
        *(ushort8*)(xh + cb) = v;
    }
}

// ---------------------------------------------------------------------------
// Kernel 2: offset conv (1 px/thread, hoisted taps, pipelined c loop),
// gathering from NCHW bf16 x.  grid (2, 32, 16) z = j*4+b.
// ---------------------------------------------------------------------------
__global__ __launch_bounds__(256) void offset_conv_kernel(
    const unsigned short* __restrict__ xbf, const float* __restrict__ owT,
    const float* __restrict__ ob, float* __restrict__ off)
{
    const int t  = threadIdx.x;
    const int lx = t & 63, ly = t >> 6;
    const int w0 = blockIdx.x * 64 + lx;
    const int h0 = blockIdx.y * 4 + ly;
    const int z  = blockIdx.z;
    const int j  = z >> 2, b = z & 3;
    const int d  = rate_of(j);

    int addr[9]; float msk[9];
#pragma unroll
    for (int tap = 0; tap < 9; ++tap) {
        const int iy = tap / 3, ix = tap % 3;
        const int xx = w0 + (ix - 1) * d;
        const int yy = h0 + (iy - 1) * d;
        const bool v = ((unsigned)xx < (unsigned)WW) && ((unsigned)yy < (unsigned)HH);
        addr[tap] = min(max(yy, 0), HH - 1) * WW + min(max(xx, 0), WW - 1);
        msk[tap]  = v ? 1.f : 0.f;
    }

    float acc[18];
#pragma unroll
    for (int o = 0; o < 18; ++o) acc[o] = ob[j * 18 + o];

    const unsigned short* xb = xbf + (size_t)b * CIN * HWP;
    float p[9];
#pragma unroll
    for (int tap = 0; tap < 9; ++tap) p[tap] = bf2f(xb[addr[tap]]);

    for (int c = 0; c < CIN; ++c) {
        const unsigned short* xn = xb + (c < CIN - 1 ? c + 1 : CIN - 1) * HWP;
        float q[9];
#pragma unroll
        for (int tap = 0; tap < 9; ++tap) q[tap] = bf2f(xn[addr[tap]]);

        const float* wp = owT + ((j * 64 + c) * 9) * 18;
#pragma unroll
        for (int tap = 0; tap < 9; ++tap) {
            const float v = p[tap] * msk[tap];
            const float* wt = wp + tap * 18;
#pragma unroll
            for (int o = 0; o < 18; ++o)
                acc[o] = fmaf(v, wt[o], acc[o]);
        }
#pragma unroll
        for (int tap = 0; tap < 9; ++tap) p[tap] = q[tap];
    }

    float* op = off + (size_t)z * 18 * HWP + h0 * WW + w0;
#pragma unroll
    for (int o = 0; o < 18; ++o) op[o * HWP] = fmaxf(acc[o], 0.f);
}

// ---------------------------------------------------------------------------
// Kernel 3: deformable conv, im2col-in-LDS + bf16 MFMA, 2D tiles,
// channel-last gathers: one (corner, 8ch) chunk = one 16B dwordx4 load.
// Block = 256 thr = 4 waves; one (b,i), pixel tile = 2 rows x 64 cols.
// Thread (spx 0..127, cg 0..1) samples 32 channels via 4 corners x 4
// ushort8 loads, packs bf16 into S[row][px][72-pad].
// MFMA: wave wv owns o-subtile; 8 n-tiles x 2 k-chunks per tap.
// grid = (128 tiles, 16 z), z = i*4+b.
// Layouts (HW-verified): A[m=lane&15][k=quad*8+j], B[k=quad*8+j][n=lane&15],
// D[m=quad*4+r][n=lane&15].
// ---------------------------------------------------------------------------
__global__ __launch_bounds__(256) void deform_mfma_kernel(
    const unsigned short* __restrict__ xhwc, const short* __restrict__ wtb,
    const float* __restrict__ off, unsigned short* __restrict__ cat)
{
    __shared__ __align__(16) short S[2][64][72];   // 18,432 B

    const int t  = threadIdx.x;
    const int z  = blockIdx.y;
    const int i  = z >> 2, b = z & 3;
    const int d  = rate_of(i);
    const int j  = (i + 3) & 3;
    const int ty = blockIdx.x >> 1;    // row-pair 0..63
    const int tx = blockIdx.x & 1;     // col-half 0..1

    // sampling role
    const int spx = t & 127;           // local pixel 0..127
    const int cg  = t >> 7;            // channel half 0..1
    const int sly = spx >> 6, slx = spx & 63;
    const int ph  = ty * 2 + sly, pw = tx * 64 + slx;
    const int pg  = ph * WW + pw;

    // mfma role
    const int wv = t >> 6, lane = t & 63;
    const int nl = lane & 15, quad = lane >> 4;

    const unsigned short* xh = xhwc + (size_t)b * HWP * 64;
    const float* offp = off + ((size_t)(j * 4 + b) * 18) * HWP + pg;

    f32x4 acc[8];
#pragma unroll
    for (int nt = 0; nt < 8; ++nt) acc[nt] = (f32x4){0.f, 0.f, 0.f, 0.f};

    for (int k = 0; k < 9; ++k) {
        // ---- bilinear geometry for this thread's pixel ----
        const int iy = k / 3, ix = k % 3;
        float dy = offp[(2 * k) * HWP];
        float dx = offp[(2 * k + 1) * HWP];
        float py = (float)(ph + (iy - 1) * d) + dy;
        float px = (float)(pw + (ix - 1) * d) + dx;
        float fy0 = floorf(py), fx0 = floorf(px);
        float wy1 = py - fy0, wx1 = px - fx0;
        float wy0 = 1.f - wy1, wx0 = 1.f - wx1;
        int y0 = (int)fy0, x0 = (int)fx0;
        int y1 = y0 + 1,  x1 = x0 + 1;
        bool vy0 = (unsigned)y0 < (unsigned)HH, vy1 = (unsigned)y1 < (unsigned)HH;
        bool vx0 = (unsigned)x0 < (unsigned)WW, vx1 = (unsigned)x1 < (unsigned)WW;
        int yc0 = min(max(y0, 0), HH - 1), yc1 = min(max(y1, 0), HH - 1);
        int xc0 = min(max(x0, 0), WW - 1), xc1 = min(max(x1, 0), WW - 1);
        float w00 = (vy0 && vx0) ? wy0 * wx0 : 0.f;
        float w01 = (vy0 && vx1) ? wy0 * wx1 : 0.f;
        float w10 = (vy1 && vx0) ? wy1 * wx0 : 0.f;
        float w11 = (vy1 && vx1) ? wy1 * wx1 : 0.f;
        // channel-last corner base pointers
        const unsigned short* pc00 = xh + (size_t)(yc0 * WW + xc0) * 64;
        const unsigned short* pc01 = xh + (size_t)(yc0 * WW + xc1) * 64;
        const unsigned short* pc10 = xh + (size_t)(yc1 * WW + xc0) * 64;
        const unsigned short* pc11 = xh + (size_t)(yc1 * WW + xc1) * 64;

        if (k) __syncthreads();   // previous tap's MFMAs done with S

        // ---- sample this thread's 32 channels: 4 chunks x 4 corner loads --
#pragma unroll
        for (int ch = 0; ch < 4; ++ch) {
            const int cb = cg * 32 + ch * 8;
            ushort8 u00 = *(const ushort8*)(pc00 + cb);
            ushort8 u01 = *(const ushort8*)(pc01 + cb);
            ushort8 u10 = *(const ushort8*)(pc10 + cb);
            ushort8 u11 = *(const ushort8*)(pc11 + cb);
            short8 pk;
#pragma unroll
            for (int cj = 0; cj < 8; ++cj) {
                float v = bf2f(u00[cj]) * w00 + bf2f(u01[cj]) * w01
                        + bf2f(u10[cj]) * w10 + bf2f(u11[cj]) * w11;
                pk[cj] = f2bf(v);
            }
            *(__shared__ short8*)&S[sly][slx][cb] = pk;
        }
        __syncthreads();

        // ---- MFMA: 16 o-rows x 128 pixels, K=64 in 2 chunks ----
        const short* wrow = wtb + ((size_t)((i * 64 + wv * 16 + nl) * 9 + k)) * 64;
#pragma unroll
        for (int q2 = 0; q2 < 2; ++q2) {
            short8 a = *(const short8*)&wrow[q2 * 32 + quad * 8];
#pragma unroll
            for (int nt = 0; nt < 8; ++nt) {
                short8 bfr = *(const __shared__ short8*)
                    &S[nt >> 2][(nt & 3) * 16 + nl][q2 * 32 + quad * 8];
                acc[nt] = __builtin_amdgcn_mfma_f32_16x16x32_bf16(a, bfr, acc[nt], 0, 0, 0);
            }
        }
    }

    // ---- store D[m=quad*4+r][n=nl] as bf16 CAT ----
#pragma unroll
    for (int nt = 0; nt < 8; ++nt) {
        const int prow = ty * 2 + (nt >> 2);
        const int pcol = tx * 64 + (nt & 3) * 16 + nl;
        unsigned short* cp = cat
            + ((size_t)(b * 256 + i * 64 + wv * 16 + quad * 4)) * HWP
            + prow * WW + pcol;
#pragma unroll
        for (int r = 0; r < 4; ++r)
            cp[(size_t)r * HWP] = (unsigned short)f2bf(acc[nt][r]);
    }
}

// ---------------------------------------------------------------------------
// Kernel 4: per-(b,channel) spatial mean of bf16 CAT.  1024 blocks x 256.
// ---------------------------------------------------------------------------
__global__ __launch_bounds__(256) void reduce_kernel(
    const unsigned short* __restrict__ cat, float* __restrict__ g)
{
    const int bc = blockIdx.x;
    const unsigned short* p = cat + (size_t)bc * HWP;
    float s = 0.f;
#pragma unroll
    for (int q = 0; q < 8; ++q) {
        short8 v8 = *(const short8*)(p + q * 2048 + threadIdx.x * 8);
#pragma unroll
        for (int e = 0; e < 8; ++e) s += bf2f((unsigned short)v8[e]);
    }
#pragma unroll
    for (int o = 32; o > 0; o >>= 1) s += __shfl_down(s, o, 64);
    __shared__ float ls[4];
    if ((threadIdx.x & 63) == 0) ls[threadIdx.x >> 6] = s;
    __syncthreads();
    if (threadIdx.x == 0) {
        g[bc] = (ls[0] + ls[1] + ls[2] + ls[3]) * (1.f / (float)HWP);
    }
}

// ---------------------------------------------------------------------------
// Kernel 5: SE MLP.
// ---------------------------------------------------------------------------
__global__ __launch_bounds__(256) void se_kernel(
    const float* __restrict__ g,  const float* __restrict__ w1,
    const float* __restrict__ b1, const float* __restrict__ w2,
    const float* __restrict__ b2, float* __restrict__ scale)
{
    __shared__ float gs[1024];
    __shared__ float h1s[256];
    const int t = threadIdx.x;
#pragma unroll
    for (int q = 0; q < 4; ++q) gs[q * 256 + t] = g[q * 256 + t];
    __syncthreads();
    {
        int b = t >> 6, o = t & 63;
        float a = b1[o];
        for (int c = 0; c < 256; ++c)
            a = fmaf(gs[b * 256 + c], w1[o * 256 + c], a);
        h1s[t] = fmaxf(a, 0.f);
    }
    __syncthreads();
#pragma unroll
    for (int q = 0; q < 4; ++q) {
        int idx = q * 256 + t;
        int b = idx >> 8, cc = idx & 255;
        float a = b2[cc];
#pragma unroll 8
        for (int o = 0; o < 64; ++o)
            a = fmaf(h1s[b * 64 + o], w2[cc * 64 + o], a);
        scale[idx] = 1.f + 1.f / (1.f + expf(-a));
    }
}

// ---------------------------------------------------------------------------
// Kernel 6: gated sum epilogue (bf16 CAT).
// ---------------------------------------------------------------------------
__global__ __launch_bounds__(256) void final_kernel(
    const float* __restrict__ x, const unsigned short* __restrict__ cat,
    const float* __restrict__ scale, float* __restrict__ out)
{
    const int gid = blockIdx.x;
    const int p = (gid & 63) * 256 + threadIdx.x;
    const int c = (gid >> 6) & 63;
    const int b = gid >> 12;
    const float s0 = scale[b * 256 + c];
    const float s1 = scale[b * 256 + 64 + c];
    const float s2 = scale[b * 256 + 128 + c];
    const float s3 = scale[b * 256 + 192 + c];
    const unsigned short* cb = cat + ((size_t)(b * 256 + c)) * HWP + p;
    float v = x[(size_t)(b * 64 + c) * HWP + p];
    v = fmaf(s0, bf2f(cb[0 * 64 * HWP]), v);
    v = fmaf(s1, bf2f(cb[1 * 64 * HWP]), v);
    v = fmaf(s2, bf2f(cb[2 * 64 * HWP]), v);
    v = fmaf(s3, bf2f(cb[3 * 64 * HWP]), v);
    out[(size_t)(b * 64 + c) * HWP + p] = v;
}

extern "C" void kernel_launch(void* const* d_in, const int* in_sizes, int n_in,
                              void* d_out, int out_size, void* d_ws, size_t ws_size,
                              hipStream_t stream) {
    const float* x  = (const float*)d_in[0];
    const float* dw = (const float*)d_in[1];
    const float* ow = (const float*)d_in[2];
    const float* ob = (const float*)d_in[3];
    const float* w1 = (const float*)d_in[4];
    const float* b1 = (const float*)d_in[5];
    const float* w2 = (const float*)d_in[6];
    const float* b2 = (const float*)d_in[7];
    float* out = (float*)d_out;
    float* ws  = (float*)d_ws;

    float* OFF            = ws + OFF_OFF;
    unsigned short* CAT   = (unsigned short*)(ws + CAT_OFF);
    unsigned short* XBF   = (unsigned short*)(ws + XBF_OFF);
    unsigned short* XHWC  = (unsigned short*)(ws + XHWC_OFF);
    short* WTB            = (short*)(ws + WTB_OFF);
    float* OWT            = ws + OWT_OFF;
    float* G              = ws + G_OFF;
    float* SCALE          = ws + SCALE_OFF;

    prep_kernel<<<17122, 256, 0, stream>>>(x, dw, ow, XBF, WTB, OWT);
    xhwc_kernel<<<dim3(256, 4), 256, 0, stream>>>(x, XHWC);
    offset_conv_kernel<<<dim3(2, 32, 16), 256, 0, stream>>>(XBF, OWT, ob, OFF);
    deform_mfma_kernel<<<dim3(128, 16), 256, 0, stream>>>(XHWC, WTB, OFF, CAT);
    reduce_kernel<<<1024, 256, 0, stream>>>(CAT, G);
    se_kernel<<<1, 256, 0, stream>>>(G, w1, b1, w2, b2, SCALE);
    final_kernel<<<16384, 256, 0, stream>>>(x, CAT, SCALE, out);
}

// Round 6
// 342.083 us; speedup vs baseline: 2.4935x; 1.0701x over previous
//
#include <hip/hip_runtime.h>
#include <hip/hip_bf16.h>
#include <math.h>

// Problem constants
#define BATCH 4
#define CIN 64
#define HH 128
#define WW 128
#define HWP (HH*WW)   // 16384

// ws layout (float indices):
//  OFF  : [4][B][18][HW] fp32     at OFF_OFF   (4,718,592 floats)
//  CAT  : [B][256][HW]  bf16      at CAT_OFF   (16,777,216 ushorts = 8,388,608 floats)
//  XBF  : [B][64][HW]   bf16      at XBF_OFF
//  XHWC : [B][HW][64]   bf16      at XHWC_OFF
//  WTB  : [4][64][9][64] bf16     at WTB_OFF
//  OWT  : [4][64][9][18] fp32     at OWT_OFF
//  G, SCALE : [B][256] fp32
#define OFF_OFF   0
#define CAT_OFF   4718592
#define XBF_OFF   (CAT_OFF + 8388608)
#define XHWC_OFF  (XBF_OFF + 2097152)
#define WTB_OFF   (CAT_OFF + 16777216)
#define OWT_OFF   (WTB_OFF + 147456)
#define G_OFF     (OWT_OFF + 41472)
#define SCALE_OFF (G_OFF + 1024)

typedef __attribute__((ext_vector_type(8))) short short8;
typedef __attribute__((ext_vector_type(8))) unsigned short ushort8;
typedef __attribute__((ext_vector_type(4))) float f32x4;

__device__ __forceinline__ int rate_of(int i) {
    return (i == 0) ? 2 : (i == 1) ? 3 : (i == 2) ? 5 : 9;
}

// fp32 -> bf16 (RNE, finite inputs only)
__device__ __forceinline__ short f2bf(float f) {
    union { float f; unsigned u; } v; v.f = f;
    unsigned u = v.u + 0x7FFFu + ((v.u >> 16) & 1u);
    return (short)(u >> 16);
}
__device__ __forceinline__ float bf2f(unsigned short u) {
    union { unsigned u; float f; } v; v.u = ((unsigned)u) << 16;
    return v.f;
}

// ---------------------------------------------------------------------------
// Kernel 1: prep — XBF = bf16(x) [NCHW]; WTB = bf16 A-layout dw; OWT fp32.
// ---------------------------------------------------------------------------
__global__ __launch_bounds__(256) void prep_kernel(
    const float* __restrict__ x,  const float* __restrict__ dw,
    const float* __restrict__ ow, unsigned short* __restrict__ xbf,
    short* __restrict__ wtb, float* __restrict__ owT)
{
    int idx = blockIdx.x * 256 + threadIdx.x;
    if (idx < 4194304) {
        xbf[idx] = (unsigned short)f2bf(x[idx]);
        return;
    }
    int idx1 = idx - 4194304;
    if (idx1 < 147456) {
        int c = idx1 & 63;
        int k = (idx1 >> 6) % 9;
        int r = idx1 / 576;
        int o = r & 63;
        int i = r >> 6;
        wtb[idx1] = f2bf(dw[((i * 64 + o) * 64 + c) * 9 + k]);
        return;
    }
    int idx2 = idx1 - 147456;
    if (idx2 < 41472) {
        int o = idx2 % 18;
        int r = idx2 / 18;
        int tap = r % 9; r /= 9;
        int c = r & 63;
        int j = r >> 6;
        owT[idx2] = ow[((j * 18 + o) * 64 + c) * 9 + tap];
    }
}

// ---------------------------------------------------------------------------
// Kernel 1b: XHWC[b][p][c] = bf16(x[b][c][p]) — channel-last copy.
// ---------------------------------------------------------------------------
__global__ __launch_bounds__(256) void xhwc_kernel(
    const float* __restrict__ x, unsigned short* __restrict__ xhwc)
{
    const int t  = threadIdx.x;
    const int b  = blockIdx.y;
    const int p0 = blockIdx.x * 64;
    const int px = t & 63;
    const int cO = t >> 6;

    const float* xb = x + (size_t)b * CIN * HWP + p0 + px;
    unsigned short* xh = xhwc + ((size_t)b * HWP + p0 + px) * 64;

#pragma unroll
    for (int g = 0; g < 2; ++g) {
        const int cb = cO * 8 + g * 32;
        ushort8 v;
#pragma unroll
        for (int cj = 0; cj < 8; ++cj)
            v[cj] = (unsigned short)f2bf(xb[(size_t)(cb + cj) * HWP]);
        *(ushort8*)(xh + cb) = v;
    }
}

// ---------------------------------------------------------------------------
// Kernel 2: offset conv (1 px/thread, hoisted taps, pipelined c loop),
// gathering from NCHW bf16 x.  grid (2, 32, 16) z = j*4+b.
// ---------------------------------------------------------------------------
__global__ __launch_bounds__(256) void offset_conv_kernel(
    const unsigned short* __restrict__ xbf, const float* __restrict__ owT,
    const float* __restrict__ ob, float* __restrict__ off)
{
    const int t  = threadIdx.x;
    const int lx = t & 63, ly = t >> 6;
    const int w0 = blockIdx.x * 64 + lx;
    const int h0 = blockIdx.y * 4 + ly;
    const int z  = blockIdx.z;
    const int j  = z >> 2, b = z & 3;
    const int d  = rate_of(j);

    int addr[9]; float msk[9];
#pragma unroll
    for (int tap = 0; tap < 9; ++tap) {
        const int iy = tap / 3, ix = tap % 3;
        const int xx = w0 + (ix - 1) * d;
        const int yy = h0 + (iy - 1) * d;
        const bool v = ((unsigned)xx < (unsigned)WW) && ((unsigned)yy < (unsigned)HH);
        addr[tap] = min(max(yy, 0), HH - 1) * WW + min(max(xx, 0), WW - 1);
        msk[tap]  = v ? 1.f : 0.f;
    }

    float acc[18];
#pragma unroll
    for (int o = 0; o < 18; ++o) acc[o] = ob[j * 18 + o];

    const unsigned short* xb = xbf + (size_t)b * CIN * HWP;
    float p[9];
#pragma unroll
    for (int tap = 0; tap < 9; ++tap) p[tap] = bf2f(xb[addr[tap]]);

    for (int c = 0; c < CIN; ++c) {
        const unsigned short* xn = xb + (c < CIN - 1 ? c + 1 : CIN - 1) * HWP;
        float q[9];
#pragma unroll
        for (int tap = 0; tap < 9; ++tap) q[tap] = bf2f(xn[addr[tap]]);

        const float* wp = owT + ((j * 64 + c) * 9) * 18;
#pragma unroll
        for (int tap = 0; tap < 9; ++tap) {
            const float v = p[tap] * msk[tap];
            const float* wt = wp + tap * 18;
#pragma unroll
            for (int o = 0; o < 18; ++o)
                acc[o] = fmaf(v, wt[o], acc[o]);
        }
#pragma unroll
        for (int tap = 0; tap < 9; ++tap) p[tap] = q[tap];
    }

    float* op = off + (size_t)z * 18 * HWP + h0 * WW + w0;
#pragma unroll
    for (int o = 0; o < 18; ++o) op[o * HWP] = fmaxf(acc[o], 0.f);
}

// ---------------------------------------------------------------------------
// Kernel 3: deformable conv, im2col-in-LDS + bf16 MFMA, 2D tiles.
// Coalesced gather mapping: 8 lanes per pixel, lane%8 = channel-octet, so
// each 16B gather instruction's 64 lanes cover 8 pixels x full 128B lines
// (8 unique lines/instr instead of 64).  Geometry computed redundantly by
// the 8 lanes of a pixel.
// MFMA wave-split by PIXELS: wave wv owns px [wv*32,+32), all 64 o-rows.
// B-frags: 4 ds_read_b128/thread/tap (was 16); A-frags: 8 16B global loads
// from L1-resident WTB.
// Block 256 thr, tile = 2 rows x 64 cols (128 px), grid (128, 16) z=i*4+b.
// Layouts (HW-verified): A[m=lane&15][k=quad*8+j], B[k=quad*8+j][n=lane&15],
// D[m=quad*4+r][n=lane&15].
// ---------------------------------------------------------------------------
__global__ __launch_bounds__(256) void deform_mfma_kernel(
    const unsigned short* __restrict__ xhwc, const short* __restrict__ wtb,
    const float* __restrict__ off, unsigned short* __restrict__ cat)
{
    __shared__ __align__(16) short S[128][72];   // [px][ch], 18,432 B

    const int t  = threadIdx.x;
    const int z  = blockIdx.y;
    const int i  = z >> 2, b = z & 3;
    const int d  = rate_of(i);
    const int j  = (i + 3) & 3;
    const int ty = blockIdx.x >> 1;    // row-pair 0..63
    const int tx = blockIdx.x & 1;     // col-half 0..1

    // sampling role: 8 lanes per pixel, lane%8 = channel-octet
    const int chunk = t & 7;           // c-octet 0..7
    const int pxb   = t >> 3;          // pixel 0..31 (+32/iter)

    // mfma role
    const int wv = t >> 6, lane = t & 63;
    const int nl = lane & 15, quad = lane >> 4;

    const unsigned short* xh = xhwc + (size_t)b * HWP * 64;
    const float* offb = off + ((size_t)(j * 4 + b) * 18) * HWP;

    f32x4 acc[8];                      // [mt][nt]
#pragma unroll
    for (int a = 0; a < 8; ++a) acc[a] = (f32x4){0.f, 0.f, 0.f, 0.f};

    for (int k = 0; k < 9; ++k) {
        const int iy = k / 3, ix = k % 3;

        if (k) __syncthreads();        // previous tap's MFMAs done with S

        // ---- sampling: 4 iters x (1 pixel, 8 channels) per thread ----
#pragma unroll
        for (int it = 0; it < 4; ++it) {
            const int psub = it * 32 + pxb;
            const int sly = psub >> 6, slx = psub & 63;
            const int ph = ty * 2 + sly, pw = tx * 64 + slx;
            const int pg = ph * WW + pw;

            float dy = offb[(2 * k) * HWP + pg];
            float dx = offb[(2 * k + 1) * HWP + pg];
            float py = (float)(ph + (iy - 1) * d) + dy;
            float px = (float)(pw + (ix - 1) * d) + dx;
            float fy0 = floorf(py), fx0 = floorf(px);
            float wy1 = py - fy0, wx1 = px - fx0;
            float wy0 = 1.f - wy1, wx0 = 1.f - wx1;
            int y0 = (int)fy0, x0 = (int)fx0;
            int y1 = y0 + 1,  x1 = x0 + 1;
            bool vy0 = (unsigned)y0 < (unsigned)HH, vy1 = (unsigned)y1 < (unsigned)HH;
            bool vx0 = (unsigned)x0 < (unsigned)WW, vx1 = (unsigned)x1 < (unsigned)WW;
            int yc0 = min(max(y0, 0), HH - 1), yc1 = min(max(y1, 0), HH - 1);
            int xc0 = min(max(x0, 0), WW - 1), xc1 = min(max(x1, 0), WW - 1);
            float w00 = (vy0 && vx0) ? wy0 * wx0 : 0.f;
            float w01 = (vy0 && vx1) ? wy0 * wx1 : 0.f;
            float w10 = (vy1 && vx0) ? wy1 * wx0 : 0.f;
            float w11 = (vy1 && vx1) ? wy1 * wx1 : 0.f;

            const int cb = chunk * 8;
            ushort8 u00 = *(const ushort8*)(xh + (size_t)(yc0 * WW + xc0) * 64 + cb);
            ushort8 u01 = *(const ushort8*)(xh + (size_t)(yc0 * WW + xc1) * 64 + cb);
            ushort8 u10 = *(const ushort8*)(xh + (size_t)(yc1 * WW + xc0) * 64 + cb);
            ushort8 u11 = *(const ushort8*)(xh + (size_t)(yc1 * WW + xc1) * 64 + cb);

            short8 pk;
#pragma unroll
            for (int cj = 0; cj < 8; ++cj) {
                float v = bf2f(u00[cj]) * w00 + bf2f(u01[cj]) * w01
                        + bf2f(u10[cj]) * w10 + bf2f(u11[cj]) * w11;
                pk[cj] = f2bf(v);
            }
            *(__shared__ short8*)&S[psub][cb] = pk;
        }
        __syncthreads();

        // ---- MFMA: wave wv -> pixels [wv*32,+32), all 64 o ----
#pragma unroll
        for (int q2 = 0; q2 < 2; ++q2) {
            short8 b0 = *(const __shared__ short8*)&S[wv * 32 + nl][q2 * 32 + quad * 8];
            short8 b1 = *(const __shared__ short8*)&S[wv * 32 + 16 + nl][q2 * 32 + quad * 8];
#pragma unroll
            for (int mt = 0; mt < 4; ++mt) {
                const short* wrow = wtb
                    + ((size_t)((i * 64 + mt * 16 + nl) * 9 + k)) * 64;
                short8 a = *(const short8*)&wrow[q2 * 32 + quad * 8];
                acc[mt * 2 + 0] = __builtin_amdgcn_mfma_f32_16x16x32_bf16(a, b0, acc[mt * 2 + 0], 0, 0, 0);
                acc[mt * 2 + 1] = __builtin_amdgcn_mfma_f32_16x16x32_bf16(a, b1, acc[mt * 2 + 1], 0, 0, 0);
            }
        }
    }

    // ---- store: o = mt*16+quad*4+r, pixel = wv*32+nt*16+nl ----
#pragma unroll
    for (int mt = 0; mt < 4; ++mt) {
#pragma unroll
        for (int nt = 0; nt < 2; ++nt) {
            const int psub = wv * 32 + nt * 16 + nl;
            const int prow = ty * 2 + (psub >> 6);
            const int pcol = tx * 64 + (psub & 63);
            unsigned short* cp = cat
                + ((size_t)(b * 256 + i * 64 + mt * 16 + quad * 4)) * HWP
                + prow * WW + pcol;
            const f32x4 v = acc[mt * 2 + nt];
#pragma unroll
            for (int r = 0; r < 4; ++r)
                cp[(size_t)r * HWP] = (unsigned short)f2bf(v[r]);
        }
    }
}

// ---------------------------------------------------------------------------
// Kernel 4: per-(b,channel) spatial mean of bf16 CAT.  1024 blocks x 256.
// ---------------------------------------------------------------------------
__global__ __launch_bounds__(256) void reduce_kernel(
    const unsigned short* __restrict__ cat, float* __restrict__ g)
{
    const int bc = blockIdx.x;
    const unsigned short* p = cat + (size_t)bc * HWP;
    float s = 0.f;
#pragma unroll
    for (int q = 0; q < 8; ++q) {
        short8 v8 = *(const short8*)(p + q * 2048 + threadIdx.x * 8);
#pragma unroll
        for (int e = 0; e < 8; ++e) s += bf2f((unsigned short)v8[e]);
    }
#pragma unroll
    for (int o = 32; o > 0; o >>= 1) s += __shfl_down(s, o, 64);
    __shared__ float ls[4];
    if ((threadIdx.x & 63) == 0) ls[threadIdx.x >> 6] = s;
    __syncthreads();
    if (threadIdx.x == 0) {
        g[bc] = (ls[0] + ls[1] + ls[2] + ls[3]) * (1.f / (float)HWP);
    }
}

// ---------------------------------------------------------------------------
// Kernel 5: SE MLP.
// ---------------------------------------------------------------------------
__global__ __launch_bounds__(256) void se_kernel(
    const float* __restrict__ g,  const float* __restrict__ w1,
    const float* __restrict__ b1, const float* __restrict__ w2,
    const float* __restrict__ b2, float* __restrict__ scale)
{
    __shared__ float gs[1024];
    __shared__ float h1s[256];
    const int t = threadIdx.x;
#pragma unroll
    for (int q = 0; q < 4; ++q) gs[q * 256 + t] = g[q * 256 + t];
    __syncthreads();
    {
        int b = t >> 6, o = t & 63;
        float a = b1[o];
        for (int c = 0; c < 256; ++c)
            a = fmaf(gs[b * 256 + c], w1[o * 256 + c], a);
        h1s[t] = fmaxf(a, 0.f);
    }
    __syncthreads();
#pragma unroll
    for (int q = 0; q < 4; ++q) {
        int idx = q * 256 + t;
        int b = idx >> 8, cc = idx & 255;
        float a = b2[cc];
#pragma unroll 8
        for (int o = 0; o < 64; ++o)
            a = fmaf(h1s[b * 64 + o], w2[cc * 64 + o], a);
        scale[idx] = 1.f + 1.f / (1.f + expf(-a));
    }
}

// ---------------------------------------------------------------------------
// Kernel 6: gated sum epilogue (bf16 CAT).
// ---------------------------------------------------------------------------
__global__ __launch_bounds__(256) void final_kernel(
    const float* __restrict__ x, const unsigned short* __restrict__ cat,
    const float* __restrict__ scale, float* __restrict__ out)
{
    const int gid = blockIdx.x;
    const int p = (gid & 63) * 256 + threadIdx.x;
    const int c = (gid >> 6) & 63;
    const int b = gid >> 12;
    const float s0 = scale[b * 256 + c];
    const float s1 = scale[b * 256 + 64 + c];
    const float s2 = scale[b * 256 + 128 + c];
    const float s3 = scale[b * 256 + 192 + c];
    const unsigned short* cb = cat + ((size_t)(b * 256 + c)) * HWP + p;
    float v = x[(size_t)(b * 64 + c) * HWP + p];
    v = fmaf(s0, bf2f(cb[0 * 64 * HWP]), v);
    v = fmaf(s1, bf2f(cb[1 * 64 * HWP]), v);
    v = fmaf(s2, bf2f(cb[2 * 64 * HWP]), v);
    v = fmaf(s3, bf2f(cb[3 * 64 * HWP]), v);
    out[(size_t)(b * 64 + c) * HWP + p] = v;
}

extern "C" void kernel_launch(void* const* d_in, const int* in_sizes, int n_in,
                              void* d_out, int out_size, void* d_ws, size_t ws_size,
                              hipStream_t stream) {
    const float* x  = (const float*)d_in[0];
    const float* dw = (const float*)d_in[1];
    const float* ow = (const float*)d_in[2];
    const float* ob = (const float*)d_in[3];
    const float* w1 = (const float*)d_in[4];
    const float* b1 = (const float*)d_in[5];
    const float* w2 = (const float*)d_in[6];
    const float* b2 = (const float*)d_in[7];
    float* out = (float*)d_out;
    float* ws  = (float*)d_ws;

    float* OFF            = ws + OFF_OFF;
    unsigned short* CAT   = (unsigned short*)(ws + CAT_OFF);
    unsigned short* XBF   = (unsigned short*)(ws + XBF_OFF);
    unsigned short* XHWC  = (unsigned short*)(ws + XHWC_OFF);
    short* WTB            = (short*)(ws + WTB_OFF);
    float* OWT            = ws + OWT_OFF;
    float* G              = ws + G_OFF;
    float* SCALE          = ws + SCALE_OFF;

    prep_kernel<<<17122, 256, 0, stream>>>(x, dw, ow, XBF, WTB, OWT);
    xhwc_kernel<<<dim3(256, 4), 256, 0, stream>>>(x, XHWC);
    offset_conv_kernel<<<dim3(2, 32, 16), 256, 0, stream>>>(XBF, OWT, ob, OFF);
    deform_mfma_kernel<<<dim3(128, 16), 256, 0, stream>>>(XHWC, WTB, OFF, CAT);
    reduce_kernel<<<1024, 256, 0, stream>>>(CAT, G);
    se_kernel<<<1, 256, 0, stream>>>(G, w1, b1, w2, b2, SCALE);
    final_kernel<<<16384, 256, 0, stream>>>(x, CAT, SCALE, out);
}

// Round 9
// 326.288 us; speedup vs baseline: 2.6142x; 1.0484x over previous
//
#include <hip/hip_runtime.h>
#include <hip/hip_bf16.h>
#include <math.h>

// Problem constants
#define BATCH 4
#define CIN 64
#define HH 128
#define WW 128
#define HWP (HH*WW)   // 16384

// ws layout (float indices):
//  OFF  : [4][B][18][HW] fp32     at OFF_OFF   (4,718,592 floats)
//  CAT  : [B][256][HW]  bf16      at CAT_OFF   (16,777,216 ushorts = 8,388,608 floats)
//  XHWC : [B][HW][64]   bf16      at XHWC_OFF  (4,194,304 ushorts = 2,097,152 floats)
//  WTB  : [4][64][9][64] bf16     at WTB_OFF   (deform weights, A-rows by o)
//  OWB  : [4][9][32][64] bf16     at OWB_OFF   (offset weights, o-padded 18->32)
//  G, SCALE : [B][256] fp32
#define OFF_OFF   0
#define CAT_OFF   4718592
#define XHWC_OFF  (CAT_OFF + 8388608)
#define WTB_OFF   (XHWC_OFF + 2097152)
#define OWB_OFF   (WTB_OFF + 73728)
#define G_OFF     (OWB_OFF + 36864)
#define SCALE_OFF (G_OFF + 1024)

typedef __attribute__((ext_vector_type(8))) short short8;
typedef __attribute__((ext_vector_type(8))) unsigned short ushort8;
typedef __attribute__((ext_vector_type(4))) float f32x4;

__device__ __forceinline__ int rate_of(int i) {
    return (i == 0) ? 2 : (i == 1) ? 3 : (i == 2) ? 5 : 9;
}

// fp32 -> bf16 (RNE, finite inputs only)
__device__ __forceinline__ short f2bf(float f) {
    union { float f; unsigned u; } v; v.f = f;
    unsigned u = v.u + 0x7FFFu + ((v.u >> 16) & 1u);
    return (short)(u >> 16);
}
__device__ __forceinline__ float bf2f(unsigned short u) {
    union { unsigned u; float f; } v; v.u = ((unsigned)u) << 16;
    return v.f;
}

// ---------------------------------------------------------------------------
// Kernel 1: prep — WTB bf16 (deform A-rows), OWB bf16 (offset B-rows, padded).
// WTB[((i*64+o)*9+k)*64+c] = bf16(dw[((i*64+o)*64+c)*9+k])
// OWB[((j*9+tap)*32+o)*64+c] = o<18 ? bf16(ow[((j*18+o)*64+c)*9+tap]) : 0
// 864 blocks x 256 = 147,456 + 73,728 elements exactly.
// ---------------------------------------------------------------------------
__global__ __launch_bounds__(256) void prep_kernel(
    const float* __restrict__ dw, const float* __restrict__ ow,
    short* __restrict__ wtb, short* __restrict__ owb)
{
    int idx = blockIdx.x * 256 + threadIdx.x;
    if (idx < 147456) {
        int c = idx & 63;
        int k = (idx >> 6) % 9;
        int r = idx / 576;
        int o = r & 63;
        int i = r >> 6;
        wtb[idx] = f2bf(dw[((i * 64 + o) * 64 + c) * 9 + k]);
        return;
    }
    int idx2 = idx - 147456;
    if (idx2 < 73728) {
        int c = idx2 & 63;
        int r = idx2 >> 6;
        int o = r & 31;
        int r2 = r >> 5;
        int tap = r2 % 9;
        int j = r2 / 9;
        owb[idx2] = (o < 18) ? f2bf(ow[((j * 18 + o) * 64 + c) * 9 + tap])
                             : (short)0;
    }
}

// ---------------------------------------------------------------------------
// Kernel 1b: XHWC[b][p][c] = bf16(x[b][c][p]) — channel-last copy (round-6).
// ---------------------------------------------------------------------------
__global__ __launch_bounds__(256) void xhwc_kernel(
    const float* __restrict__ x, unsigned short* __restrict__ xhwc)
{
    const int t  = threadIdx.x;
    const int b  = blockIdx.y;
    const int p0 = blockIdx.x * 64;
    const int px = t & 63;
    const int cO = t >> 6;

    const float* xb = x + (size_t)b * CIN * HWP + p0 + px;
    unsigned short* xh = xhwc + ((size_t)b * HWP + p0 + px) * 64;

#pragma unroll
    for (int g = 0; g < 2; ++g) {
        const int cb = cO * 8 + g * 32;
        ushort8 v;
#pragma unroll
        for (int cj = 0; cj < 8; ++cj)
            v[cj] = (unsigned short)f2bf(xb[(size_t)(cb + cj) * HWP]);
        *(ushort8*)(xh + cb) = v;
    }
}

// ---------------------------------------------------------------------------
// Kernel 2 (NEW THIS ROUND): offset conv via im2col-in-LDS + bf16 MFMA.
// Block 256 = 4 waves, tile = 64 px (one half-row), one (j,b).
// Per tap: stage 64px x 64c bf16 (dense shifted loads from XHWC, zero-masked
// for padding) into S2[64][72]; MFMA A = S2 px-rows (m=px), B = OWB o-rows
// (n=o, zero-padded 18->32), K=64/tap in 2 chunks; accumulate over 9 taps;
// epilogue bias+relu -> OFF fp32.  grid (256, 16) z = j*4+b.
// Layouts (HW-verified, same as passing deform): A[m=lane&15][k=quad*8+j],
// B[k=quad*8+j][n=lane&15], D[m=quad*4+r][n=lane&15].
// ---------------------------------------------------------------------------
__global__ __launch_bounds__(256) void offset_mfma_kernel(
    const unsigned short* __restrict__ xhwc, const short* __restrict__ owb,
    const float* __restrict__ ob, float* __restrict__ off)
{
    __shared__ __align__(16) short S2[64][72];   // 9216 B

    const int t  = threadIdx.x;
    const int z  = blockIdx.y;
    const int j  = z >> 2, b = z & 3;
    const int d  = rate_of(j);
    const int p0 = blockIdx.x * 64;
    const int ph = p0 >> 7;            // all tile px share this row
    const int cb0 = p0 & 127;          // col base (0 or 64)

    const int wv = t >> 6, lane = t & 63;
    const int nl = lane & 15, quad = lane >> 4;

    const unsigned short* xh = xhwc + (size_t)b * HWP * 64;

    f32x4 acc[2];
    acc[0] = (f32x4){0.f, 0.f, 0.f, 0.f};
    acc[1] = (f32x4){0.f, 0.f, 0.f, 0.f};

    for (int k = 0; k < 9; ++k) {
        const int iy = k / 3, ix = k % 3;
        const int ys = ph + (iy - 1) * d;
        const bool rowok = (unsigned)ys < (unsigned)HH;

        if (k) __syncthreads();

        // ---- stage: 512 (px,chunk) tasks, 2 per thread ----
#pragma unroll
        for (int q = 0; q < 2; ++q) {
            const int task = q * 256 + t;
            const int px = task >> 3, chunk = task & 7;
            const int xs = cb0 + px + (ix - 1) * d;
            short8 v = {};
            if (rowok && (unsigned)xs < (unsigned)WW)
                v = *(const short8*)(xh + ((size_t)(ys * WW + xs)) * 64 + chunk * 8);
            *(short8*)&S2[px][chunk * 8] = v;
        }
        __syncthreads();

        // ---- MFMA: wave wv -> px m-tile [wv*16,+16), 2 o n-tiles ----
#pragma unroll
        for (int q2 = 0; q2 < 2; ++q2) {
            short8 a = *(const short8*)&S2[wv * 16 + nl][q2 * 32 + quad * 8];
#pragma unroll
            for (int nt = 0; nt < 2; ++nt) {
                const short* brow = owb
                    + ((size_t)((j * 9 + k) * 32 + nt * 16 + nl)) * 64;
                short8 bf = *(const short8*)&brow[q2 * 32 + quad * 8];
                acc[nt] = __builtin_amdgcn_mfma_f32_16x16x32_bf16(a, bf, acc[nt], 0, 0, 0);
            }
        }
    }

    // ---- store: px = wv*16+quad*4+r, o = nt*16+nl (only o<18) ----
    float* op = off + (size_t)z * 18 * HWP + p0;
#pragma unroll
    for (int nt = 0; nt < 2; ++nt) {
        const int o = nt * 16 + nl;
        if (o < 18) {
            const float bias = ob[j * 18 + o];
#pragma unroll
            for (int r = 0; r < 4; ++r) {
                const int pxl = wv * 16 + quad * 4 + r;
                op[(size_t)o * HWP + pxl] = fmaxf(acc[nt][r] + bias, 0.f);
            }
        }
    }
}

// ---------------------------------------------------------------------------
// Kernel 3: deformable conv — ROUND-6 PASSING VERSION, verbatim.
// im2col-in-LDS + bf16 MFMA, 2D tiles; 8 lanes/pixel, lane%8 = c-octet;
// inline fp32 geometry; MFMA wave-split by pixels.
// grid (128, 16) z=i*4+b, block 256.
// ---------------------------------------------------------------------------
__global__ __launch_bounds__(256) void deform_mfma_kernel(
    const unsigned short* __restrict__ xhwc, const short* __restrict__ wtb,
    const float* __restrict__ off, unsigned short* __restrict__ cat)
{
    __shared__ __align__(16) short S[128][72];   // [px][ch], 18,432 B

    const int t  = threadIdx.x;
    const int z  = blockIdx.y;
    const int i  = z >> 2, b = z & 3;
    const int d  = rate_of(i);
    const int j  = (i + 3) & 3;
    const int ty = blockIdx.x >> 1;    // row-pair 0..63
    const int tx = blockIdx.x & 1;     // col-half 0..1

    const int chunk = t & 7;           // c-octet 0..7
    const int pxb   = t >> 3;          // pixel 0..31 (+32/iter)

    const int wv = t >> 6, lane = t & 63;
    const int nl = lane & 15, quad = lane >> 4;

    const unsigned short* xh = xhwc + (size_t)b * HWP * 64;
    const float* offb = off + ((size_t)(j * 4 + b) * 18) * HWP;

    f32x4 acc[8];                      // [mt][nt]
#pragma unroll
    for (int a = 0; a < 8; ++a) acc[a] = (f32x4){0.f, 0.f, 0.f, 0.f};

    for (int k = 0; k < 9; ++k) {
        const int iy = k / 3, ix = k % 3;

        if (k) __syncthreads();        // previous tap's MFMAs done with S

        // ---- sampling: 4 iters x (1 pixel, 8 channels) per thread ----
#pragma unroll
        for (int it = 0; it < 4; ++it) {
            const int psub = it * 32 + pxb;
            const int sly = psub >> 6, slx = psub & 63;
            const int ph = ty * 2 + sly, pw = tx * 64 + slx;
            const int pg = ph * WW + pw;

            float dy = offb[(2 * k) * HWP + pg];
            float dx = offb[(2 * k + 1) * HWP + pg];
            float py = (float)(ph + (iy - 1) * d) + dy;
            float px = (float)(pw + (ix - 1) * d) + dx;
            float fy0 = floorf(py), fx0 = floorf(px);
            float wy1 = py - fy0, wx1 = px - fx0;
            float wy0 = 1.f - wy1, wx0 = 1.f - wx1;
            int y0 = (int)fy0, x0 = (int)fx0;
            int y1 = y0 + 1,  x1 = x0 + 1;
            bool vy0 = (unsigned)y0 < (unsigned)HH, vy1 = (unsigned)y1 < (unsigned)HH;
            bool vx0 = (unsigned)x0 < (unsigned)WW, vx1 = (unsigned)x1 < (unsigned)WW;
            int yc0 = min(max(y0, 0), HH - 1), yc1 = min(max(y1, 0), HH - 1);
            int xc0 = min(max(x0, 0), WW - 1), xc1 = min(max(x1, 0), WW - 1);
            float w00 = (vy0 && vx0) ? wy0 * wx0 : 0.f;
            float w01 = (vy0 && vx1) ? wy0 * wx1 : 0.f;
            float w10 = (vy1 && vx0) ? wy1 * wx0 : 0.f;
            float w11 = (vy1 && vx1) ? wy1 * wx1 : 0.f;

            const int cb = chunk * 8;
            ushort8 u00 = *(const ushort8*)(xh + (size_t)(yc0 * WW + xc0) * 64 + cb);
            ushort8 u01 = *(const ushort8*)(xh + (size_t)(yc0 * WW + xc1) * 64 + cb);
            ushort8 u10 = *(const ushort8*)(xh + (size_t)(yc1 * WW + xc0) * 64 + cb);
            ushort8 u11 = *(const ushort8*)(xh + (size_t)(yc1 * WW + xc1) * 64 + cb);

            short8 pk;
#pragma unroll
            for (int cj = 0; cj < 8; ++cj) {
                float v = bf2f(u00[cj]) * w00 + bf2f(u01[cj]) * w01
                        + bf2f(u10[cj]) * w10 + bf2f(u11[cj]) * w11;
                pk[cj] = f2bf(v);
            }
            *(short8*)&S[psub][cb] = pk;
        }
        __syncthreads();

        // ---- MFMA: wave wv -> pixels [wv*32,+32), all 64 o ----
#pragma unroll
        for (int q2 = 0; q2 < 2; ++q2) {
            short8 b0 = *(const short8*)&S[wv * 32 + nl][q2 * 32 + quad * 8];
            short8 b1 = *(const short8*)&S[wv * 32 + 16 + nl][q2 * 32 + quad * 8];
#pragma unroll
            for (int mt = 0; mt < 4; ++mt) {
                const short* wrow = wtb
                    + ((size_t)((i * 64 + mt * 16 + nl) * 9 + k)) * 64;
                short8 a = *(const short8*)&wrow[q2 * 32 + quad * 8];
                acc[mt * 2 + 0] = __builtin_amdgcn_mfma_f32_16x16x32_bf16(a, b0, acc[mt * 2 + 0], 0, 0, 0);
                acc[mt * 2 + 1] = __builtin_amdgcn_mfma_f32_16x16x32_bf16(a, b1, acc[mt * 2 + 1], 0, 0, 0);
            }
        }
    }

    // ---- store: o = mt*16+quad*4+r, pixel = wv*32+nt*16+nl ----
#pragma unroll
    for (int mt = 0; mt < 4; ++mt) {
#pragma unroll
        for (int nt = 0; nt < 2; ++nt) {
            const int psub = wv * 32 + nt * 16 + nl;
            const int prow = ty * 2 + (psub >> 6);
            const int pcol = tx * 64 + (psub & 63);
            unsigned short* cp = cat
                + ((size_t)(b * 256 + i * 64 + mt * 16 + quad * 4)) * HWP
                + prow * WW + pcol;
            const f32x4 v = acc[mt * 2 + nt];
#pragma unroll
            for (int r = 0; r < 4; ++r)
                cp[(size_t)r * HWP] = (unsigned short)f2bf(v[r]);
        }
    }
}

// ---------------------------------------------------------------------------
// Kernel 4: per-(b,channel) spatial mean of bf16 CAT.  1024 blocks x 256.
// ---------------------------------------------------------------------------
__global__ __launch_bounds__(256) void reduce_kernel(
    const unsigned short* __restrict__ cat, float* __restrict__ g)
{
    const int bc = blockIdx.x;
    const unsigned short* p = cat + (size_t)bc * HWP;
    float s = 0.f;
#pragma unroll
    for (int q = 0; q < 8; ++q) {
        short8 v8 = *(const short8*)(p + q * 2048 + threadIdx.x * 8);
#pragma unroll
        for (int e = 0; e < 8; ++e) s += bf2f((unsigned short)v8[e]);
    }
#pragma unroll
    for (int o = 32; o > 0; o >>= 1) s += __shfl_down(s, o, 64);
    __shared__ float ls[4];
    if ((threadIdx.x & 63) == 0) ls[threadIdx.x >> 6] = s;
    __syncthreads();
    if (threadIdx.x == 0) {
        g[bc] = (ls[0] + ls[1] + ls[2] + ls[3]) * (1.f / (float)HWP);
    }
}

// ---------------------------------------------------------------------------
// Kernel 5: SE MLP.
// ---------------------------------------------------------------------------
__global__ __launch_bounds__(256) void se_kernel(
    const float* __restrict__ g,  const float* __restrict__ w1,
    const float* __restrict__ b1, const float* __restrict__ w2,
    const float* __restrict__ b2, float* __restrict__ scale)
{
    __shared__ float gs[1024];
    __shared__ float h1s[256];
    const int t = threadIdx.x;
#pragma unroll
    for (int q = 0; q < 4; ++q) gs[q * 256 + t] = g[q * 256 + t];
    __syncthreads();
    {
        int b = t >> 6, o = t & 63;
        float a = b1[o];
        for (int c = 0; c < 256; ++c)
            a = fmaf(gs[b * 256 + c], w1[o * 256 + c], a);
        h1s[t] = fmaxf(a, 0.f);
    }
    __syncthreads();
#pragma unroll
    for (int q = 0; q < 4; ++q) {
        int idx = q * 256 + t;
        int b = idx >> 8, cc = idx & 255;
        float a = b2[cc];
#pragma unroll 8
        for (int o = 0; o < 64; ++o)
            a = fmaf(h1s[b * 64 + o], w2[cc * 64 + o], a);
        scale[idx] = 1.f + 1.f / (1.f + expf(-a));
    }
}

// ---------------------------------------------------------------------------
// Kernel 6: gated sum epilogue (bf16 CAT).
// ---------------------------------------------------------------------------
__global__ __launch_bounds__(256) void final_kernel(
    const float* __restrict__ x, const unsigned short* __restrict__ cat,
    const float* __restrict__ scale, float* __restrict__ out)
{
    const int gid = blockIdx.x;
    const int p = (gid & 63) * 256 + threadIdx.x;
    const int c = (gid >> 6) & 63;
    const int b = gid >> 12;
    const float s0 = scale[b * 256 + c];
    const float s1 = scale[b * 256 + 64 + c];
    const float s2 = scale[b * 256 + 128 + c];
    const float s3 = scale[b * 256 + 192 + c];
    const unsigned short* cb = cat + ((size_t)(b * 256 + c)) * HWP + p;
    float v = x[(size_t)(b * 64 + c) * HWP + p];
    v = fmaf(s0, bf2f(cb[0 * 64 * HWP]), v);
    v = fmaf(s1, bf2f(cb[1 * 64 * HWP]), v);
    v = fmaf(s2, bf2f(cb[2 * 64 * HWP]), v);
    v = fmaf(s3, bf2f(cb[3 * 64 * HWP]), v);
    out[(size_t)(b * 64 + c) * HWP + p] = v;
}

extern "C" void kernel_launch(void* const* d_in, const int* in_sizes, int n_in,
                              void* d_out, int out_size, void* d_ws, size_t ws_size,
                              hipStream_t stream) {
    const float* x  = (const float*)d_in[0];
    const float* dw = (const float*)d_in[1];
    const float* ow = (const float*)d_in[2];
    const float* ob = (const float*)d_in[3];
    const float* w1 = (const float*)d_in[4];
    const float* b1 = (const float*)d_in[5];
    const float* w2 = (const float*)d_in[6];
    const float* b2 = (const float*)d_in[7];
    float* out = (float*)d_out;
    float* ws  = (float*)d_ws;

    float* OFF            = ws + OFF_OFF;
    unsigned short* CAT   = (unsigned short*)(ws + CAT_OFF);
    unsigned short* XHWC  = (unsigned short*)(ws + XHWC_OFF);
    short* WTB            = (short*)(ws + WTB_OFF);
    short* OWB            = (short*)(ws + OWB_OFF);
    float* G              = ws + G_OFF;
    float* SCALE          = ws + SCALE_OFF;

    prep_kernel<<<864, 256, 0, stream>>>(dw, ow, WTB, OWB);
    xhwc_kernel<<<dim3(256, 4), 256, 0, stream>>>(x, XHWC);
    offset_mfma_kernel<<<dim3(256, 16), 256, 0, stream>>>(XHWC, OWB, ob, OFF);
    deform_mfma_kernel<<<dim3(128, 16), 256, 0, stream>>>(XHWC, WTB, OFF, CAT);
    reduce_kernel<<<1024, 256, 0, stream>>>(CAT, G);
    se_kernel<<<1, 256, 0, stream>>>(G, w1, b1, w2, b2, SCALE);
    final_kernel<<<16384, 256, 0, stream>>>(x, CAT, SCALE, out);
}

// Round 10
// 312.856 us; speedup vs baseline: 2.7264x; 1.0429x over previous
//
#include <hip/hip_runtime.h>
#include <hip/hip_bf16.h>
#include <math.h>

// Problem constants
#define BATCH 4
#define CIN 64
#define HH 128
#define WW 128
#define HWP (HH*WW)   // 16384

// ws layout (float indices):
//  OFF  : [4][B][18][HW] fp32     at OFF_OFF   (4,718,592 floats)
//  CAT  : [B][256][HW]  fp16      at CAT_OFF   (16,777,216 halves = 8,388,608 floats)
//  XHWC : [B][HW][64]   fp16      at XHWC_OFF  (4,194,304 halves = 2,097,152 floats)
//  WTH  : [4][64][9][64] fp16     at WTH_OFF   (deform weights, A-rows by o)
//  OWH  : [4][9][32][64] fp16     at OWH_OFF   (offset weights, o-padded 18->32)
//  G, SCALE : [B][256] fp32
#define OFF_OFF   0
#define CAT_OFF   4718592
#define XHWC_OFF  (CAT_OFF + 8388608)
#define WTH_OFF   (XHWC_OFF + 2097152)
#define OWH_OFF   (WTH_OFF + 73728)
#define G_OFF     (OWH_OFF + 36864)
#define SCALE_OFF (G_OFF + 1024)

typedef _Float16 h16x2 __attribute__((ext_vector_type(2)));
typedef _Float16 h16x8 __attribute__((ext_vector_type(8)));
typedef float    f32x4 __attribute__((ext_vector_type(4)));

union h8view { h16x8 v8; h16x2 v2[4]; };

__device__ __forceinline__ int rate_of(int i) {
    return (i == 0) ? 2 : (i == 1) ? 3 : (i == 2) ? 5 : 9;
}

// ---------------------------------------------------------------------------
// Kernel 1: prep — WTH fp16 (deform A-rows), OWH fp16 (offset B-rows, padded).
// WTH[((i*64+o)*9+k)*64+c] = fp16(dw[((i*64+o)*64+c)*9+k])
// OWH[((j*9+tap)*32+o)*64+c] = o<18 ? fp16(ow[((j*18+o)*64+c)*9+tap]) : 0
// 864 blocks x 256 = 147,456 + 73,728 elements exactly.  (round-9 indexing)
// ---------------------------------------------------------------------------
__global__ __launch_bounds__(256) void prep_kernel(
    const float* __restrict__ dw, const float* __restrict__ ow,
    _Float16* __restrict__ wth, _Float16* __restrict__ owh)
{
    int idx = blockIdx.x * 256 + threadIdx.x;
    if (idx < 147456) {
        int c = idx & 63;
        int k = (idx >> 6) % 9;
        int r = idx / 576;
        int o = r & 63;
        int i = r >> 6;
        wth[idx] = (_Float16)dw[((i * 64 + o) * 64 + c) * 9 + k];
        return;
    }
    int idx2 = idx - 147456;
    if (idx2 < 73728) {
        int c = idx2 & 63;
        int r = idx2 >> 6;
        int o = r & 31;
        int r2 = r >> 5;
        int tap = r2 % 9;
        int j = r2 / 9;
        owh[idx2] = (o < 18) ? (_Float16)ow[((j * 18 + o) * 64 + c) * 9 + tap]
                             : (_Float16)0.f;
    }
}

// ---------------------------------------------------------------------------
// Kernel 1b: XHWC[b][p][c] = fp16(x[b][c][p]) — channel-last copy (round-9
// structure, dtype swapped).
// ---------------------------------------------------------------------------
__global__ __launch_bounds__(256) void xhwc_kernel(
    const float* __restrict__ x, _Float16* __restrict__ xhwc)
{
    const int t  = threadIdx.x;
    const int b  = blockIdx.y;
    const int p0 = blockIdx.x * 64;
    const int px = t & 63;
    const int cO = t >> 6;

    const float* xb = x + (size_t)b * CIN * HWP + p0 + px;
    _Float16* xh = xhwc + ((size_t)b * HWP + p0 + px) * 64;

#pragma unroll
    for (int g = 0; g < 2; ++g) {
        const int cb = cO * 8 + g * 32;
        h16x8 v;
#pragma unroll
        for (int cj = 0; cj < 8; ++cj)
            v[cj] = (_Float16)xb[(size_t)(cb + cj) * HWP];
        *(h16x8*)(xh + cb) = v;
    }
}

// ---------------------------------------------------------------------------
// Kernel 2: offset conv via im2col-in-LDS + fp16 MFMA (round-9 structure,
// dtype swapped).  grid (256, 16) z = j*4+b.
// Layouts (HW-verified): A[m=lane&15][k=quad*8+j], B[k=quad*8+j][n=lane&15],
// D[m=quad*4+r][n=lane&15].
// ---------------------------------------------------------------------------
__global__ __launch_bounds__(256) void offset_mfma_kernel(
    const _Float16* __restrict__ xhwc, const _Float16* __restrict__ owh,
    const float* __restrict__ ob, float* __restrict__ off)
{
    __shared__ __align__(16) _Float16 S2[64][72];   // 9216 B

    const int t  = threadIdx.x;
    const int z  = blockIdx.y;
    const int j  = z >> 2, b = z & 3;
    const int d  = rate_of(j);
    const int p0 = blockIdx.x * 64;
    const int ph = p0 >> 7;            // all tile px share this row
    const int cb0 = p0 & 127;          // col base (0 or 64)

    const int wv = t >> 6, lane = t & 63;
    const int nl = lane & 15, quad = lane >> 4;

    const _Float16* xh = xhwc + (size_t)b * HWP * 64;

    f32x4 acc[2];
    acc[0] = (f32x4){0.f, 0.f, 0.f, 0.f};
    acc[1] = (f32x4){0.f, 0.f, 0.f, 0.f};

    for (int k = 0; k < 9; ++k) {
        const int iy = k / 3, ix = k % 3;
        const int ys = ph + (iy - 1) * d;
        const bool rowok = (unsigned)ys < (unsigned)HH;

        if (k) __syncthreads();

        // ---- stage: 512 (px,chunk) tasks, 2 per thread ----
#pragma unroll
        for (int q = 0; q < 2; ++q) {
            const int task = q * 256 + t;
            const int px = task >> 3, chunk = task & 7;
            const int xs = cb0 + px + (ix - 1) * d;
            h16x8 v = {};
            if (rowok && (unsigned)xs < (unsigned)WW)
                v = *(const h16x8*)(xh + ((size_t)(ys * WW + xs)) * 64 + chunk * 8);
            *(h16x8*)&S2[px][chunk * 8] = v;
        }
        __syncthreads();

        // ---- MFMA: wave wv -> px m-tile [wv*16,+16), 2 o n-tiles ----
#pragma unroll
        for (int q2 = 0; q2 < 2; ++q2) {
            h16x8 a = *(const h16x8*)&S2[wv * 16 + nl][q2 * 32 + quad * 8];
#pragma unroll
            for (int nt = 0; nt < 2; ++nt) {
                const _Float16* brow = owh
                    + ((size_t)((j * 9 + k) * 32 + nt * 16 + nl)) * 64;
                h16x8 bf = *(const h16x8*)&brow[q2 * 32 + quad * 8];
                acc[nt] = __builtin_amdgcn_mfma_f32_16x16x32_f16(a, bf, acc[nt], 0, 0, 0);
            }
        }
    }

    // ---- store: px = wv*16+quad*4+r, o = nt*16+nl (only o<18) ----
    float* op = off + (size_t)z * 18 * HWP + p0;
#pragma unroll
    for (int nt = 0; nt < 2; ++nt) {
        const int o = nt * 16 + nl;
        if (o < 18) {
            const float bias = ob[j * 18 + o];
#pragma unroll
            for (int r = 0; r < 4; ++r) {
                const int pxl = wv * 16 + quad * 4 + r;
                op[(size_t)o * HWP + pxl] = fmaxf(acc[nt][r] + bias, 0.f);
            }
        }
    }
}

// ---------------------------------------------------------------------------
// Kernel 3: deformable conv — round-9 structure VERBATIM (inline fp32
// geometry, 8 lanes/pixel, pixel-split MFMA), dtype swapped to fp16 with
// packed-half2 bilinear (v_pk ops) via union views.
// grid (128, 16) z=i*4+b, block 256.
// ---------------------------------------------------------------------------
__global__ __launch_bounds__(256) void deform_mfma_kernel(
    const _Float16* __restrict__ xhwc, const _Float16* __restrict__ wth,
    const float* __restrict__ off, _Float16* __restrict__ cat)
{
    __shared__ __align__(16) _Float16 S[128][72];   // [px][ch], 18,432 B

    const int t  = threadIdx.x;
    const int z  = blockIdx.y;
    const int i  = z >> 2, b = z & 3;
    const int d  = rate_of(i);
    const int j  = (i + 3) & 3;
    const int ty = blockIdx.x >> 1;    // row-pair 0..63
    const int tx = blockIdx.x & 1;     // col-half 0..1

    const int chunk = t & 7;           // c-octet 0..7
    const int pxb   = t >> 3;          // pixel 0..31 (+32/iter)

    const int wv = t >> 6, lane = t & 63;
    const int nl = lane & 15, quad = lane >> 4;

    const _Float16* xh = xhwc + (size_t)b * HWP * 64;
    const float* offb = off + ((size_t)(j * 4 + b) * 18) * HWP;

    f32x4 acc[8];                      // [mt][nt]
#pragma unroll
    for (int a = 0; a < 8; ++a) acc[a] = (f32x4){0.f, 0.f, 0.f, 0.f};

    for (int k = 0; k < 9; ++k) {
        const int iy = k / 3, ix = k % 3;

        if (k) __syncthreads();        // previous tap's MFMAs done with S

        // ---- sampling: 4 iters x (1 pixel, 8 channels) per thread ----
#pragma unroll
        for (int it = 0; it < 4; ++it) {
            const int psub = it * 32 + pxb;
            const int sly = psub >> 6, slx = psub & 63;
            const int ph = ty * 2 + sly, pw = tx * 64 + slx;
            const int pg = ph * WW + pw;

            float dy = offb[(2 * k) * HWP + pg];
            float dx = offb[(2 * k + 1) * HWP + pg];
            float py = (float)(ph + (iy - 1) * d) + dy;
            float px = (float)(pw + (ix - 1) * d) + dx;
            float fy0 = floorf(py), fx0 = floorf(px);
            float wy1 = py - fy0, wx1 = px - fx0;
            float wy0 = 1.f - wy1, wx0 = 1.f - wx1;
            int y0 = (int)fy0, x0 = (int)fx0;
            int y1 = y0 + 1,  x1 = x0 + 1;
            bool vy0 = (unsigned)y0 < (unsigned)HH, vy1 = (unsigned)y1 < (unsigned)HH;
            bool vx0 = (unsigned)x0 < (unsigned)WW, vx1 = (unsigned)x1 < (unsigned)WW;
            int yc0 = min(max(y0, 0), HH - 1), yc1 = min(max(y1, 0), HH - 1);
            int xc0 = min(max(x0, 0), WW - 1), xc1 = min(max(x1, 0), WW - 1);
            float w00 = (vy0 && vx0) ? wy0 * wx0 : 0.f;
            float w01 = (vy0 && vx1) ? wy0 * wx1 : 0.f;
            float w10 = (vy1 && vx0) ? wy1 * wx0 : 0.f;
            float w11 = (vy1 && vx1) ? wy1 * wx1 : 0.f;

            const _Float16 h00 = (_Float16)w00, h01 = (_Float16)w01;
            const _Float16 h10 = (_Float16)w10, h11 = (_Float16)w11;
            const h16x2 w00p = {h00, h00}, w01p = {h01, h01};
            const h16x2 w10p = {h10, h10}, w11p = {h11, h11};

            const int cb = chunk * 8;
            h8view u00, u01, u10, u11, outv;
            u00.v8 = *(const h16x8*)(xh + (size_t)(yc0 * WW + xc0) * 64 + cb);
            u01.v8 = *(const h16x8*)(xh + (size_t)(yc0 * WW + xc1) * 64 + cb);
            u10.v8 = *(const h16x8*)(xh + (size_t)(yc1 * WW + xc0) * 64 + cb);
            u11.v8 = *(const h16x8*)(xh + (size_t)(yc1 * WW + xc1) * 64 + cb);
#pragma unroll
            for (int pp = 0; pp < 4; ++pp) {
                h16x2 r = u00.v2[pp] * w00p + u01.v2[pp] * w01p
                        + u10.v2[pp] * w10p + u11.v2[pp] * w11p;
                outv.v2[pp] = r;
            }
            *(h16x8*)&S[psub][cb] = outv.v8;
        }
        __syncthreads();

        // ---- MFMA: wave wv -> pixels [wv*32,+32), all 64 o ----
#pragma unroll
        for (int q2 = 0; q2 < 2; ++q2) {
            h16x8 b0 = *(const h16x8*)&S[wv * 32 + nl][q2 * 32 + quad * 8];
            h16x8 b1 = *(const h16x8*)&S[wv * 32 + 16 + nl][q2 * 32 + quad * 8];
#pragma unroll
            for (int mt = 0; mt < 4; ++mt) {
                const _Float16* wrow = wth
                    + ((size_t)((i * 64 + mt * 16 + nl) * 9 + k)) * 64;
                h16x8 a = *(const h16x8*)&wrow[q2 * 32 + quad * 8];
                acc[mt * 2 + 0] = __builtin_amdgcn_mfma_f32_16x16x32_f16(a, b0, acc[mt * 2 + 0], 0, 0, 0);
                acc[mt * 2 + 1] = __builtin_amdgcn_mfma_f32_16x16x32_f16(a, b1, acc[mt * 2 + 1], 0, 0, 0);
            }
        }
    }

    // ---- store: o = mt*16+quad*4+r, pixel = wv*32+nt*16+nl ----
#pragma unroll
    for (int mt = 0; mt < 4; ++mt) {
#pragma unroll
        for (int nt = 0; nt < 2; ++nt) {
            const int psub = wv * 32 + nt * 16 + nl;
            const int prow = ty * 2 + (psub >> 6);
            const int pcol = tx * 64 + (psub & 63);
            _Float16* cp = cat
                + ((size_t)(b * 256 + i * 64 + mt * 16 + quad * 4)) * HWP
                + prow * WW + pcol;
            const f32x4 v = acc[mt * 2 + nt];
#pragma unroll
            for (int r = 0; r < 4; ++r)
                cp[(size_t)r * HWP] = (_Float16)v[r];
        }
    }
}

// ---------------------------------------------------------------------------
// Kernel 4: per-(b,channel) spatial mean of fp16 CAT.  1024 blocks x 256.
// ---------------------------------------------------------------------------
__global__ __launch_bounds__(256) void reduce_kernel(
    const _Float16* __restrict__ cat, float* __restrict__ g)
{
    const int bc = blockIdx.x;
    const _Float16* p = cat + (size_t)bc * HWP;
    float s = 0.f;
#pragma unroll
    for (int q = 0; q < 8; ++q) {
        h16x8 v8 = *(const h16x8*)(p + q * 2048 + threadIdx.x * 8);
#pragma unroll
        for (int e = 0; e < 8; ++e) s += (float)v8[e];
    }
#pragma unroll
    for (int o = 32; o > 0; o >>= 1) s += __shfl_down(s, o, 64);
    __shared__ float ls[4];
    if ((threadIdx.x & 63) == 0) ls[threadIdx.x >> 6] = s;
    __syncthreads();
    if (threadIdx.x == 0) {
        g[bc] = (ls[0] + ls[1] + ls[2] + ls[3]) * (1.f / (float)HWP);
    }
}

// ---------------------------------------------------------------------------
// Kernel 5: SE MLP.
// ---------------------------------------------------------------------------
__global__ __launch_bounds__(256) void se_kernel(
    const float* __restrict__ g,  const float* __restrict__ w1,
    const float* __restrict__ b1, const float* __restrict__ w2,
    const float* __restrict__ b2, float* __restrict__ scale)
{
    __shared__ float gs[1024];
    __shared__ float h1s[256];
    const int t = threadIdx.x;
#pragma unroll
    for (int q = 0; q < 4; ++q) gs[q * 256 + t] = g[q * 256 + t];
    __syncthreads();
    {
        int b = t >> 6, o = t & 63;
        float a = b1[o];
        for (int c = 0; c < 256; ++c)
            a = fmaf(gs[b * 256 + c], w1[o * 256 + c], a);
        h1s[t] = fmaxf(a, 0.f);
    }
    __syncthreads();
#pragma unroll
    for (int q = 0; q < 4; ++q) {
        int idx = q * 256 + t;
        int b = idx >> 8, cc = idx & 255;
        float a = b2[cc];
#pragma unroll 8
        for (int o = 0; o < 64; ++o)
            a = fmaf(h1s[b * 64 + o], w2[cc * 64 + o], a);
        scale[idx] = 1.f + 1.f / (1.f + expf(-a));
    }
}

// ---------------------------------------------------------------------------
// Kernel 6: gated sum epilogue (fp16 CAT).
// ---------------------------------------------------------------------------
__global__ __launch_bounds__(256) void final_kernel(
    const float* __restrict__ x, const _Float16* __restrict__ cat,
    const float* __restrict__ scale, float* __restrict__ out)
{
    const int gid = blockIdx.x;
    const int p = (gid & 63) * 256 + threadIdx.x;
    const int c = (gid >> 6) & 63;
    const int b = gid >> 12;
    const float s0 = scale[b * 256 + c];
    const float s1 = scale[b * 256 + 64 + c];
    const float s2 = scale[b * 256 + 128 + c];
    const float s3 = scale[b * 256 + 192 + c];
    const _Float16* cb = cat + ((size_t)(b * 256 + c)) * HWP + p;
    float v = x[(size_t)(b * 64 + c) * HWP + p];
    v = fmaf(s0, (float)cb[0 * 64 * HWP], v);
    v = fmaf(s1, (float)cb[1 * 64 * HWP], v);
    v = fmaf(s2, (float)cb[2 * 64 * HWP], v);
    v = fmaf(s3, (float)cb[3 * 64 * HWP], v);
    out[(size_t)(b * 64 + c) * HWP + p] = v;
}

extern "C" void kernel_launch(void* const* d_in, const int* in_sizes, int n_in,
                              void* d_out, int out_size, void* d_ws, size_t ws_size,
                              hipStream_t stream) {
    const float* x  = (const float*)d_in[0];
    const float* dw = (const float*)d_in[1];
    const float* ow = (const float*)d_in[2];
    const float* ob = (const float*)d_in[3];
    const float* w1 = (const float*)d_in[4];
    const float* b1 = (const float*)d_in[5];
    const float* w2 = (const float*)d_in[6];
    const float* b2 = (const float*)d_in[7];
    float* out = (float*)d_out;
    float* ws  = (float*)d_ws;

    float* OFF      = ws + OFF_OFF;
    _Float16* CAT   = (_Float16*)(ws + CAT_OFF);
    _Float16* XHWC  = (_Float16*)(ws + XHWC_OFF);
    _Float16* WTH   = (_Float16*)(ws + WTH_OFF);
    _Float16* OWH   = (_Float16*)(ws + OWH_OFF);
    float* G        = ws + G_OFF;
    float* SCALE    = ws + SCALE_OFF;

    prep_kernel<<<864, 256, 0, stream>>>(dw, ow, WTH, OWH);
    xhwc_kernel<<<dim3(256, 4), 256, 0, stream>>>(x, XHWC);
    offset_mfma_kernel<<<dim3(256, 16), 256, 0, stream>>>(XHWC, OWH, ob, OFF);
    deform_mfma_kernel<<<dim3(128, 16), 256, 0, stream>>>(XHWC, WTH, OFF, CAT);
    reduce_kernel<<<1024, 256, 0, stream>>>(CAT, G);
    se_kernel<<<1, 256, 0, stream>>>(G, w1, b1, w2, b2, SCALE);
    final_kernel<<<16384, 256, 0, stream>>>(x, CAT, SCALE, out);
}

// Round 11
// 305.411 us; speedup vs baseline: 2.7929x; 1.0244x over previous
//
#include <hip/hip_runtime.h>
#include <hip/hip_bf16.h>
#include <math.h>

// Problem constants
#define BATCH 4
#define CIN 64
#define HH 128
#define WW 128
#define HWP (HH*WW)   // 16384

// ws layout (float indices):
//  OFF  : [4][B][18][HW] fp32     at OFF_OFF   (4,718,592 floats)
//  CAT  : [B][256][HW]  fp16      at CAT_OFF   (16,777,216 halves = 8,388,608 floats)
//  XHWC : [B][HW][64]   fp16      at XHWC_OFF  (4,194,304 halves = 2,097,152 floats)
//  WTH  : [4][64][9][64] fp16     at WTH_OFF   (deform weights, A-rows by o)
//  OWH  : [4][9][32][64] fp16     at OWH_OFF   (offset weights, o-padded 18->32)
//  G, SCALE : [B][256] fp32
#define OFF_OFF   0
#define CAT_OFF   4718592
#define XHWC_OFF  (CAT_OFF + 8388608)
#define WTH_OFF   (XHWC_OFF + 2097152)
#define OWH_OFF   (WTH_OFF + 73728)
#define G_OFF     (OWH_OFF + 36864)
#define SCALE_OFF (G_OFF + 1024)

typedef _Float16 h16x2 __attribute__((ext_vector_type(2)));
typedef _Float16 h16x8 __attribute__((ext_vector_type(8)));
typedef float    f32x4 __attribute__((ext_vector_type(4)));

union h8view { h16x8 v8; h16x2 v2[4]; };

__device__ __forceinline__ int rate_of(int i) {
    return (i == 0) ? 2 : (i == 1) ? 3 : (i == 2) ? 5 : 9;
}

// ---------------------------------------------------------------------------
// Kernel 1: prep — WTH fp16 (deform A-rows), OWH fp16 (offset B-rows, padded).
// (round-10 passing version, verbatim)
// ---------------------------------------------------------------------------
__global__ __launch_bounds__(256) void prep_kernel(
    const float* __restrict__ dw, const float* __restrict__ ow,
    _Float16* __restrict__ wth, _Float16* __restrict__ owh)
{
    int idx = blockIdx.x * 256 + threadIdx.x;
    if (idx < 147456) {
        int c = idx & 63;
        int k = (idx >> 6) % 9;
        int r = idx / 576;
        int o = r & 63;
        int i = r >> 6;
        wth[idx] = (_Float16)dw[((i * 64 + o) * 64 + c) * 9 + k];
        return;
    }
    int idx2 = idx - 147456;
    if (idx2 < 73728) {
        int c = idx2 & 63;
        int r = idx2 >> 6;
        int o = r & 31;
        int r2 = r >> 5;
        int tap = r2 % 9;
        int j = r2 / 9;
        owh[idx2] = (o < 18) ? (_Float16)ow[((j * 18 + o) * 64 + c) * 9 + tap]
                             : (_Float16)0.f;
    }
}

// ---------------------------------------------------------------------------
// Kernel 1b: XHWC[b][p][c] = fp16(x[b][c][p]) — channel-last copy.
// (round-10 passing version, verbatim)
// ---------------------------------------------------------------------------
__global__ __launch_bounds__(256) void xhwc_kernel(
    const float* __restrict__ x, _Float16* __restrict__ xhwc)
{
    const int t  = threadIdx.x;
    const int b  = blockIdx.y;
    const int p0 = blockIdx.x * 64;
    const int px = t & 63;
    const int cO = t >> 6;

    const float* xb = x + (size_t)b * CIN * HWP + p0 + px;
    _Float16* xh = xhwc + ((size_t)b * HWP + p0 + px) * 64;

#pragma unroll
    for (int g = 0; g < 2; ++g) {
        const int cb = cO * 8 + g * 32;
        h16x8 v;
#pragma unroll
        for (int cj = 0; cj < 8; ++cj)
            v[cj] = (_Float16)xb[(size_t)(cb + cj) * HWP];
        *(h16x8*)(xh + cb) = v;
    }
}

// ---------------------------------------------------------------------------
// Kernel 2: offset conv via im2col-in-LDS + fp16 MFMA — NOW SOFTWARE-
// PIPELINED: double-buffered S2, ONE barrier per tap.  Loop body: issue
// tap k+1 staging loads into regs -> MFMA tap k from S2[k&1] -> store regs
// to S2[(k+1)&1] -> barrier.  grid (256, 16) z = j*4+b.
// Layouts (HW-verified): A[m=lane&15][k=quad*8+j], B[k=quad*8+j][n=lane&15],
// D[m=quad*4+r][n=lane&15].
// ---------------------------------------------------------------------------
__global__ __launch_bounds__(256) void offset_mfma_kernel(
    const _Float16* __restrict__ xhwc, const _Float16* __restrict__ owh,
    const float* __restrict__ ob, float* __restrict__ off)
{
    __shared__ __align__(16) _Float16 S2[2][64][72];   // 18,432 B

    const int t  = threadIdx.x;
    const int z  = blockIdx.y;
    const int j  = z >> 2, b = z & 3;
    const int d  = rate_of(j);
    const int p0 = blockIdx.x * 64;
    const int ph = p0 >> 7;            // all tile px share this row
    const int cb0 = p0 & 127;          // col base (0 or 64)

    const int wv = t >> 6, lane = t & 63;
    const int nl = lane & 15, quad = lane >> 4;

    const _Float16* xh = xhwc + (size_t)b * HWP * 64;

    f32x4 acc[2];
    acc[0] = (f32x4){0.f, 0.f, 0.f, 0.f};
    acc[1] = (f32x4){0.f, 0.f, 0.f, 0.f};

    h16x8 v[2];

    auto stage_load = [&](int kk) {
        const int iy = kk / 3, ix = kk % 3;
        const int ys = ph + (iy - 1) * d;
        const bool rowok = (unsigned)ys < (unsigned)HH;
#pragma unroll
        for (int q = 0; q < 2; ++q) {
            const int task = q * 256 + t;
            const int px = task >> 3, ch = task & 7;
            const int xs = cb0 + px + (ix - 1) * d;
            h16x8 vv = {};
            if (rowok && (unsigned)xs < (unsigned)WW)
                vv = *(const h16x8*)(xh + ((size_t)(ys * WW + xs)) * 64 + ch * 8);
            v[q] = vv;
        }
    };
    auto stage_store = [&](int buf) {
#pragma unroll
        for (int q = 0; q < 2; ++q) {
            const int task = q * 256 + t;
            const int px = task >> 3, ch = task & 7;
            *(h16x8*)&S2[buf][px][ch * 8] = v[q];
        }
    };

    // prologue: tap 0
    stage_load(0);
    stage_store(0);
    __syncthreads();

    for (int k = 0; k < 9; ++k) {
        if (k < 8) stage_load(k + 1);        // VMEM in flight during MFMA

        // ---- MFMA: wave wv -> px m-tile [wv*16,+16), 2 o n-tiles ----
#pragma unroll
        for (int q2 = 0; q2 < 2; ++q2) {
            h16x8 a = *(const h16x8*)&S2[k & 1][wv * 16 + nl][q2 * 32 + quad * 8];
#pragma unroll
            for (int nt = 0; nt < 2; ++nt) {
                const _Float16* brow = owh
                    + ((size_t)((j * 9 + k) * 32 + nt * 16 + nl)) * 64;
                h16x8 bf = *(const h16x8*)&brow[q2 * 32 + quad * 8];
                acc[nt] = __builtin_amdgcn_mfma_f32_16x16x32_f16(a, bf, acc[nt], 0, 0, 0);
            }
        }

        if (k < 8) stage_store((k + 1) & 1);
        __syncthreads();
    }

    // ---- store: px = wv*16+quad*4+r, o = nt*16+nl (only o<18) ----
    float* op = off + (size_t)z * 18 * HWP + p0;
#pragma unroll
    for (int nt = 0; nt < 2; ++nt) {
        const int o = nt * 16 + nl;
        if (o < 18) {
            const float bias = ob[j * 18 + o];
#pragma unroll
            for (int r = 0; r < 4; ++r) {
                const int pxl = wv * 16 + quad * 4 + r;
                op[(size_t)o * HWP + pxl] = fmaxf(acc[nt][r] + bias, 0.f);
            }
        }
    }
}

// ---------------------------------------------------------------------------
// Kernel 3: deformable conv — round-10 dataflow, SOFTWARE-PIPELINED:
// double-buffered S, ONE barrier per tap.  Loop body: geometry + gather
// loads for tap k+1 into regs (dy/dx for k+2 prefetched a tap ahead) ->
// MFMA tap k from S[k&1] (covers gather latency) -> blend + store
// S[(k+1)&1] -> barrier.  Race-free: iter-k MFMA reads S[k&1]; next write
// to that buffer is iter-(k+1)'s store, separated by the barrier.
// grid (128, 16) z=i*4+b, block 256.
// ---------------------------------------------------------------------------
__global__ __launch_bounds__(256) void deform_mfma_kernel(
    const _Float16* __restrict__ xhwc, const _Float16* __restrict__ wth,
    const float* __restrict__ off, _Float16* __restrict__ cat)
{
    __shared__ __align__(16) _Float16 S[2][128][72];   // 36,864 B

    const int t  = threadIdx.x;
    const int z  = blockIdx.y;
    const int i  = z >> 2, b = z & 3;
    const int d  = rate_of(i);
    const int j  = (i + 3) & 3;
    const int ty = blockIdx.x >> 1;    // row-pair 0..63
    const int tx = blockIdx.x & 1;     // col-half 0..1

    const int chunk = t & 7;           // c-octet 0..7
    const int pxb   = t >> 3;          // pixel 0..31 (+32/iter)
    const int cb    = chunk * 8;

    const int wv = t >> 6, lane = t & 63;
    const int nl = lane & 15, quad = lane >> 4;

    const _Float16* xh = xhwc + (size_t)b * HWP * 64;
    const float* offb = off + ((size_t)(j * 4 + b) * 18) * HWP;

    // this thread's 4 pixels (it*32 + pxb)
    int phv[4], pwv[4], pgv[4];
#pragma unroll
    for (int it = 0; it < 4; ++it) {
        const int psub = it * 32 + pxb;
        phv[it] = ty * 2 + (psub >> 6);
        pwv[it] = tx * 64 + (psub & 63);
        pgv[it] = phv[it] * WW + pwv[it];
    }

    f32x4 acc[8];                      // [mt][nt]
#pragma unroll
    for (int a = 0; a < 8; ++a) acc[a] = (f32x4){0.f, 0.f, 0.f, 0.f};

    h8view u[4][4];                    // in-flight gather data [it][corner]
    h16x2  wp[4][4];                   // packed bilinear weights [it][corner]
    float  ocy[4], ocx[4];             // dy,dx for the tap being gathered
    float  ony[4], onx[4];             // dy,dx prefetch one tap ahead

    // geometry + gather-issue for tap kk using ocy/ocx
    auto gather = [&](int kk) {
        const int iy = kk / 3, ix = kk % 3;
#pragma unroll
        for (int it = 0; it < 4; ++it) {
            float py = (float)(phv[it] + (iy - 1) * d) + ocy[it];
            float px = (float)(pwv[it] + (ix - 1) * d) + ocx[it];
            float fy0 = floorf(py), fx0 = floorf(px);
            float wy1 = py - fy0, wx1 = px - fx0;
            float wy0 = 1.f - wy1, wx0 = 1.f - wx1;
            int y0 = (int)fy0, x0 = (int)fx0;
            int y1 = y0 + 1,  x1 = x0 + 1;
            bool vy0 = (unsigned)y0 < (unsigned)HH, vy1 = (unsigned)y1 < (unsigned)HH;
            bool vx0 = (unsigned)x0 < (unsigned)WW, vx1 = (unsigned)x1 < (unsigned)WW;
            int yc0 = min(max(y0, 0), HH - 1), yc1 = min(max(y1, 0), HH - 1);
            int xc0 = min(max(x0, 0), WW - 1), xc1 = min(max(x1, 0), WW - 1);
            float w00 = (vy0 && vx0) ? wy0 * wx0 : 0.f;
            float w01 = (vy0 && vx1) ? wy0 * wx1 : 0.f;
            float w10 = (vy1 && vx0) ? wy1 * wx0 : 0.f;
            float w11 = (vy1 && vx1) ? wy1 * wx1 : 0.f;
            const _Float16 h00 = (_Float16)w00, h01 = (_Float16)w01;
            const _Float16 h10 = (_Float16)w10, h11 = (_Float16)w11;
            wp[it][0] = (h16x2){h00, h00};
            wp[it][1] = (h16x2){h01, h01};
            wp[it][2] = (h16x2){h10, h10};
            wp[it][3] = (h16x2){h11, h11};
            u[it][0].v8 = *(const h16x8*)(xh + (size_t)(yc0 * WW + xc0) * 64 + cb);
            u[it][1].v8 = *(const h16x8*)(xh + (size_t)(yc0 * WW + xc1) * 64 + cb);
            u[it][2].v8 = *(const h16x8*)(xh + (size_t)(yc1 * WW + xc0) * 64 + cb);
            u[it][3].v8 = *(const h16x8*)(xh + (size_t)(yc1 * WW + xc1) * 64 + cb);
        }
    };

    // blend in packed half2 and store to S[buf]
    auto blendstore = [&](int buf) {
#pragma unroll
        for (int it = 0; it < 4; ++it) {
            h8view outv;
#pragma unroll
            for (int pp = 0; pp < 4; ++pp)
                outv.v2[pp] = u[it][0].v2[pp] * wp[it][0] + u[it][1].v2[pp] * wp[it][1]
                            + u[it][2].v2[pp] * wp[it][2] + u[it][3].v2[pp] * wp[it][3];
            *(h16x8*)&S[buf][it * 32 + pxb][cb] = outv.v8;
        }
    };

    // ---- prologue: tap 0 ----
#pragma unroll
    for (int it = 0; it < 4; ++it) {
        ocy[it] = offb[0 * HWP + pgv[it]];
        ocx[it] = offb[1 * HWP + pgv[it]];
    }
    gather(0);
    blendstore(0);
#pragma unroll
    for (int it = 0; it < 4; ++it) {       // offsets for tap 1
        ocy[it] = offb[2 * HWP + pgv[it]];
        ocx[it] = offb[3 * HWP + pgv[it]];
    }
    __syncthreads();

    for (int k = 0; k < 9; ++k) {
        if (k < 8) {
            gather(k + 1);                 // gathers in flight during MFMA
            if (k < 7) {
#pragma unroll
                for (int it = 0; it < 4; ++it) {
                    ony[it] = offb[(2 * (k + 2)) * HWP + pgv[it]];
                    onx[it] = offb[(2 * (k + 2) + 1) * HWP + pgv[it]];
                }
            }
        }

        // ---- MFMA: wave wv -> pixels [wv*32,+32), all 64 o, tap k ----
#pragma unroll
        for (int q2 = 0; q2 < 2; ++q2) {
            h16x8 b0 = *(const h16x8*)&S[k & 1][wv * 32 + nl][q2 * 32 + quad * 8];
            h16x8 b1 = *(const h16x8*)&S[k & 1][wv * 32 + 16 + nl][q2 * 32 + quad * 8];
#pragma unroll
            for (int mt = 0; mt < 4; ++mt) {
                const _Float16* wrow = wth
                    + ((size_t)((i * 64 + mt * 16 + nl) * 9 + k)) * 64;
                h16x8 a = *(const h16x8*)&wrow[q2 * 32 + quad * 8];
                acc[mt * 2 + 0] = __builtin_amdgcn_mfma_f32_16x16x32_f16(a, b0, acc[mt * 2 + 0], 0, 0, 0);
                acc[mt * 2 + 1] = __builtin_amdgcn_mfma_f32_16x16x32_f16(a, b1, acc[mt * 2 + 1], 0, 0, 0);
            }
        }

        if (k < 8) {
            blendstore((k + 1) & 1);
#pragma unroll
            for (int it = 0; it < 4; ++it) { ocy[it] = ony[it]; ocx[it] = onx[it]; }
        }
        __syncthreads();
    }

    // ---- store: o = mt*16+quad*4+r, pixel = wv*32+nt*16+nl ----
#pragma unroll
    for (int mt = 0; mt < 4; ++mt) {
#pragma unroll
        for (int nt = 0; nt < 2; ++nt) {
            const int psub = wv * 32 + nt * 16 + nl;
            const int prow = ty * 2 + (psub >> 6);
            const int pcol = tx * 64 + (psub & 63);
            _Float16* cp = cat
                + ((size_t)(b * 256 + i * 64 + mt * 16 + quad * 4)) * HWP
                + prow * WW + pcol;
            const f32x4 v = acc[mt * 2 + nt];
#pragma unroll
            for (int r = 0; r < 4; ++r)
                cp[(size_t)r * HWP] = (_Float16)v[r];
        }
    }
}

// ---------------------------------------------------------------------------
// Kernel 4: per-(b,channel) spatial mean of fp16 CAT.  1024 blocks x 256.
// ---------------------------------------------------------------------------
__global__ __launch_bounds__(256) void reduce_kernel(
    const _Float16* __restrict__ cat, float* __restrict__ g)
{
    const int bc = blockIdx.x;
    const _Float16* p = cat + (size_t)bc * HWP;
    float s = 0.f;
#pragma unroll
    for (int q = 0; q < 8; ++q) {
        h16x8 v8 = *(const h16x8*)(p + q * 2048 + threadIdx.x * 8);
#pragma unroll
        for (int e = 0; e < 8; ++e) s += (float)v8[e];
    }
#pragma unroll
    for (int o = 32; o > 0; o >>= 1) s += __shfl_down(s, o, 64);
    __shared__ float ls[4];
    if ((threadIdx.x & 63) == 0) ls[threadIdx.x >> 6] = s;
    __syncthreads();
    if (threadIdx.x == 0) {
        g[bc] = (ls[0] + ls[1] + ls[2] + ls[3]) * (1.f / (float)HWP);
    }
}

// ---------------------------------------------------------------------------
// Kernel 5: SE MLP.
// ---------------------------------------------------------------------------
__global__ __launch_bounds__(256) void se_kernel(
    const float* __restrict__ g,  const float* __restrict__ w1,
    const float* __restrict__ b1, const float* __restrict__ w2,
    const float* __restrict__ b2, float* __restrict__ scale)
{
    __shared__ float gs[1024];
    __shared__ float h1s[256];
    const int t = threadIdx.x;
#pragma unroll
    for (int q = 0; q < 4; ++q) gs[q * 256 + t] = g[q * 256 + t];
    __syncthreads();
    {
        int b = t >> 6, o = t & 63;
        float a = b1[o];
        for (int c = 0; c < 256; ++c)
            a = fmaf(gs[b * 256 + c], w1[o * 256 + c], a);
        h1s[t] = fmaxf(a, 0.f);
    }
    __syncthreads();
#pragma unroll
    for (int q = 0; q < 4; ++q) {
        int idx = q * 256 + t;
        int b = idx >> 8, cc = idx & 255;
        float a = b2[cc];
#pragma unroll 8
        for (int o = 0; o < 64; ++o)
            a = fmaf(h1s[b * 64 + o], w2[cc * 64 + o], a);
        scale[idx] = 1.f + 1.f / (1.f + expf(-a));
    }
}

// ---------------------------------------------------------------------------
// Kernel 6: gated sum epilogue (fp16 CAT).
// ---------------------------------------------------------------------------
__global__ __launch_bounds__(256) void final_kernel(
    const float* __restrict__ x, const _Float16* __restrict__ cat,
    const float* __restrict__ scale, float* __restrict__ out)
{
    const int gid = blockIdx.x;
    const int p = (gid & 63) * 256 + threadIdx.x;
    const int c = (gid >> 6) & 63;
    const int b = gid >> 12;
    const float s0 = scale[b * 256 + c];
    const float s1 = scale[b * 256 + 64 + c];
    const float s2 = scale[b * 256 + 128 + c];
    const float s3 = scale[b * 256 + 192 + c];
    const _Float16* cb = cat + ((size_t)(b * 256 + c)) * HWP + p;
    float v = x[(size_t)(b * 64 + c) * HWP + p];
    v = fmaf(s0, (float)cb[0 * 64 * HWP], v);
    v = fmaf(s1, (float)cb[1 * 64 * HWP], v);
    v = fmaf(s2, (float)cb[2 * 64 * HWP], v);
    v = fmaf(s3, (float)cb[3 * 64 * HWP], v);
    out[(size_t)(b * 64 + c) * HWP + p] = v;
}

extern "C" void kernel_launch(void* const* d_in, const int* in_sizes, int n_in,
                              void* d_out, int out_size, void* d_ws, size_t ws_size,
                              hipStream_t stream) {
    const float* x  = (const float*)d_in[0];
    const float* dw = (const float*)d_in[1];
    const float* ow = (const float*)d_in[2];
    const float* ob = (const float*)d_in[3];
    const float* w1 = (const float*)d_in[4];
    const float* b1 = (const float*)d_in[5];
    const float* w2 = (const float*)d_in[6];
    const float* b2 = (const float*)d_in[7];
    float* out = (float*)d_out;
    float* ws  = (float*)d_ws;

    float* OFF      = ws + OFF_OFF;
    _Float16* CAT   = (_Float16*)(ws + CAT_OFF);
    _Float16* XHWC  = (_Float16*)(ws + XHWC_OFF);
    _Float16* WTH   = (_Float16*)(ws + WTH_OFF);
    _Float16* OWH   = (_Float16*)(ws + OWH_OFF);
    float* G        = ws + G_OFF;
    float* SCALE    = ws + SCALE_OFF;

    prep_kernel<<<864, 256, 0, stream>>>(dw, ow, WTH, OWH);
    xhwc_kernel<<<dim3(256, 4), 256, 0, stream>>>(x, XHWC);
    offset_mfma_kernel<<<dim3(256, 16), 256, 0, stream>>>(XHWC, OWH, ob, OFF);
    deform_mfma_kernel<<<dim3(128, 16), 256, 0, stream>>>(XHWC, WTH, OFF, CAT);
    reduce_kernel<<<1024, 256, 0, stream>>>(CAT, G);
    se_kernel<<<1, 256, 0, stream>>>(G, w1, b1, w2, b2, SCALE);
    final_kernel<<<16384, 256, 0, stream>>>(x, CAT, SCALE, out);
}